// Round 18
// baseline (953.739 us; speedup 1.0000x reference)
//
#include <hip/hip_runtime.h>

#define T_LEN 4096
#define HKn   16
#define HVn   32
#define DKn   128
#define DVn   128
#define QKVn  8192
#define NCH   64
#define CS    64

typedef __attribute__((ext_vector_type(8))) short short8;
typedef __attribute__((ext_vector_type(4))) float f32x4;
typedef __attribute__((ext_vector_type(4))) unsigned u32x4;

// ---------------- ws byte offsets ----------------
#define OFF_QSH  ((size_t)0)                    // [HK][T][DK] u16
#define OFF_QSL  ((size_t)16777216)
#define OFF_KSH  ((size_t)33554432)
#define OFF_KSL  ((size_t)50331648)
#define OFF_KTH  ((size_t)67108864)             // [HK][DK][T] u16
#define OFF_KTL  ((size_t)83886080)
#define OFF_VA   ((size_t)100663296)            // [HV][T][DV] f32 (beta*v -> U in place)
#define OFF_GBL  ((size_t)167772160)            // [HV][T] float2 (beta, logLam)
#define OFF_G    ((size_t)168820736)            // [HV][T] f32 cumsum G
#define OFF_WH   ((size_t)169345024)            // [HV][NCH][CS][DK] u16 (negated W)
#define OFF_WL   ((size_t)202899456)
#define OFF_MH   ((size_t)236453888)            // [HV][NCH][CS][CS] u16
#define OFF_ML   ((size_t)253231104)
// end ~270MB

// ---------------- helpers ----------------
template <int CTRL>
__device__ __forceinline__ float dpp_add(float x) {
    int v = __builtin_amdgcn_update_dpp(0, __float_as_int(x), CTRL, 0xF, 0xF, true);
    return x + __int_as_float(v);
}
__device__ __forceinline__ float reduce32g(float x) {
    x = dpp_add<0x128>(x); x = dpp_add<0x124>(x);
    x = dpp_add<0x122>(x); x = dpp_add<0x121>(x);
    int v = __builtin_amdgcn_ds_swizzle(__float_as_int(x), 0x401F);
    return x + __int_as_float(v);
}
__device__ __forceinline__ unsigned short bf16rne(float f) {
    unsigned x = __float_as_uint(f);
    return (unsigned short)((x + 0x7FFFu + ((x >> 16) & 1u)) >> 16);
}
__device__ __forceinline__ float bf16tof(unsigned short h) {
    return __uint_as_float(((unsigned)h) << 16);
}
__device__ __forceinline__ void bsplit(float f, unsigned short& h, unsigned short& l) {
    h = bf16rne(f);
    l = bf16rne(f - bf16tof(h));
}
__device__ __forceinline__ unsigned packsplit(float f) {
    unsigned short h, l; bsplit(f, h, l);
    return ((unsigned)h << 16) | (unsigned)l;
}
__device__ __forceinline__ f32x4 MF(short8 a, short8 b, f32x4 c) {
    return __builtin_amdgcn_mfma_f32_16x16x32_bf16(a, b, c, 0, 0, 0);
}
// unpack 8 packed u32 (hi<<16|lo) -> hi short8, lo short8
__device__ __forceinline__ void unpack8(u32x4 x0, u32x4 x1, short8& hi, short8& lo) {
    union { u32x4 u; short8 s; } H, L;
    H.u[0] = __builtin_amdgcn_perm(x0.y, x0.x, 0x07060302u);
    L.u[0] = __builtin_amdgcn_perm(x0.y, x0.x, 0x05040100u);
    H.u[1] = __builtin_amdgcn_perm(x0.w, x0.z, 0x07060302u);
    L.u[1] = __builtin_amdgcn_perm(x0.w, x0.z, 0x05040100u);
    H.u[2] = __builtin_amdgcn_perm(x1.y, x1.x, 0x07060302u);
    L.u[2] = __builtin_amdgcn_perm(x1.y, x1.x, 0x05040100u);
    H.u[3] = __builtin_amdgcn_perm(x1.w, x1.z, 0x07060302u);
    L.u[3] = __builtin_amdgcn_perm(x1.w, x1.z, 0x05040100u);
    hi = H.s; lo = L.s;
}
#define SB0() __builtin_amdgcn_sched_barrier(0)
// raw barrier: drain LDS only; in-flight global loads survive
#define BARL() do { \
    asm volatile("s_waitcnt lgkmcnt(0)" ::: "memory"); \
    __builtin_amdgcn_s_barrier(); \
    asm volatile("" ::: "memory"); \
} while (0)

// volatile (issue-pinned, spill-safe) loads — ext-vector types only
__device__ __forceinline__ short8 vld16(const unsigned short* p) {
    return *(const volatile short8*)p;
}
__device__ __forceinline__ f32x4 vld16f(const float* p) {
    return *(const volatile f32x4*)p;
}
__device__ __forceinline__ float vld4(const float* p) {
    return *(const volatile float*)p;
}

// ---------------- prep: gating ----------------
__global__ __launch_bounds__(256) void k_gate(
    const float* __restrict__ a, const float* __restrict__ b,
    const float* __restrict__ dt_bias, const float* __restrict__ alog,
    float2* __restrict__ gbl)
{
    const int i = blockIdx.x * 256 + threadIdx.x;
    if (i < T_LEN * HVn) {
        const int h = i >> 12, t = i & (T_LEN - 1);
        const float av = a[(size_t)t * HVn + h];
        const float bv = b[(size_t)t * HVn + h];
        const float xv = av + dt_bias[h];
        const float sp = fmaxf(xv, 0.f) + log1pf(expf(-fabsf(xv)));
        const float g  = -expf(alog[h]) * sp;          // log lambda
        const float beta = 1.f / (1.f + expf(-bv));
        gbl[(size_t)h * T_LEN + t] = make_float2(beta, g);
    }
}

// ---------------- prep: conv + SiLU + L2norm, bf16-split q/k, beta*v ----------------
__global__ __launch_bounds__(128) void k_conv(
    const float* __restrict__ x, const float* __restrict__ w,
    const float* __restrict__ bgate,
    unsigned short* __restrict__ qsh, unsigned short* __restrict__ qsl,
    unsigned short* __restrict__ ksh, unsigned short* __restrict__ ksl,
    float* __restrict__ va2)
{
    const int t = blockIdx.x, seg = blockIdx.y, d = threadIdx.x;
    const int c = seg * 128 + d;
    const float4 w4 = ((const float4*)w)[c];
    float acc;
    if (t >= 3) {
        const float* xc = x + (size_t)(t - 3) * QKVn + c;
        acc = fmaf(w4.x, xc[0], fmaf(w4.y, xc[(size_t)QKVn],
              fmaf(w4.z, xc[(size_t)2 * QKVn], w4.w * xc[(size_t)3 * QKVn])));
    } else {
        float a0 = (t - 3 >= 0) ? x[(size_t)(t - 3) * QKVn + c] : 0.f;
        float a1 = (t - 2 >= 0) ? x[(size_t)(t - 2) * QKVn + c] : 0.f;
        float a2 = (t - 1 >= 0) ? x[(size_t)(t - 1) * QKVn + c] : 0.f;
        float a3 = x[(size_t)t * QKVn + c];
        acc = fmaf(w4.x, a0, fmaf(w4.y, a1, fmaf(w4.z, a2, w4.w * a3)));
    }
    const float y = acc / (1.f + expf(-acc));

    if (seg < 32) {
        float ss = reduce32g(y * y);
        __shared__ float part[4];
        if ((threadIdx.x & 31) == 0) part[threadIdx.x >> 5] = ss;
        __syncthreads();
        const float total = part[0] + part[1] + part[2] + part[3];
        const float r = rsqrtf(total + 1e-6f);
        float o = y * r;
        unsigned short hh, ll;
        if (seg < 16) {
            o *= 0.08838834764831845f;
            bsplit(o, hh, ll);
            const size_t idx = ((size_t)seg * T_LEN + t) * DKn + d;
            qsh[idx] = hh; qsl[idx] = ll;
        } else {
            bsplit(o, hh, ll);
            const size_t idx = ((size_t)(seg - 16) * T_LEN + t) * DKn + d;
            ksh[idx] = hh; ksl[idx] = ll;
        }
    } else {
        const int h = seg - 32;
        const float bv = bgate[(size_t)t * HVn + h];
        const float beta = 1.f / (1.f + expf(-bv));
        va2[((size_t)h * T_LEN + t) * DVn + d] = y * beta;
    }
}

// ---------------- transpose k -> [HK][DK][T] ----------------
__global__ __launch_bounds__(256) void k_tr(
    const unsigned short* __restrict__ ksh, const unsigned short* __restrict__ ksl,
    unsigned short* __restrict__ kth, unsigned short* __restrict__ ktl)
{
    __shared__ unsigned pk[64][65];
    const int b = blockIdx.x;
    const int kh = b >> 7, tt = (b >> 1) & 63, hh = b & 1;
    const int t0 = tt * 64, d0 = hh * 64;
    const int tid = threadIdx.x;
    #pragma unroll
    for (int e = 0; e < 16; ++e) {
        const int lin = e * 256 + tid;
        const int tl = lin >> 6, dl = lin & 63;
        const size_t o = ((size_t)kh * T_LEN + t0 + tl) * DKn + d0 + dl;
        pk[tl][dl] = ((unsigned)ksh[o] << 16) | (unsigned)ksl[o];
    }
    __syncthreads();
    #pragma unroll
    for (int e = 0; e < 16; ++e) {
        const int lin = e * 256 + tid;
        const int dl = lin >> 6, tl = lin & 63;
        const unsigned v = pk[tl][dl];
        const size_t o = ((size_t)kh * DKn + d0 + dl) * T_LEN + t0 + tl;
        kth[o] = (unsigned short)(v >> 16);
        ktl[o] = (unsigned short)(v & 0xFFFF);
    }
}

// ---------------- phase 1: per (head, chunk): G, A, M, solve -> U (in va2), -W ----------------
__global__ __launch_bounds__(256) void k_p1(
    const float2* __restrict__ gbl,
    const unsigned short* __restrict__ qsh, const unsigned short* __restrict__ qsl,
    const unsigned short* __restrict__ ksh, const unsigned short* __restrict__ ksl,
    float* __restrict__ va2, float* __restrict__ Gbuf,
    unsigned short* __restrict__ Wh, unsigned short* __restrict__ Wl,
    unsigned short* __restrict__ Mh, unsigned short* __restrict__ Ml)
{
    __shared__ float sA[64][68];
    __shared__ float sG[64];
    __shared__ float sB[64];
    const int blk = blockIdx.x;
    const int h = blk >> 6, ch = blk & 63;
    const int kh = h >> 1, t0 = ch * 64;
    const int tid = threadIdx.x, lane = tid & 63, wid = tid >> 6;
    const int l15 = lane & 15, lg = lane >> 4;

    if (tid < 64) {
        float2 g2 = gbl[(size_t)h * T_LEN + t0 + tid];
        sB[tid] = g2.x;
        float G = g2.y;
        #pragma unroll
        for (int s = 1; s < 64; s <<= 1) {
            float y = __int_as_float(__builtin_amdgcn_ds_bpermute((tid - s) << 2, __float_as_int(G)));
            G += (tid >= s) ? y : 0.f;
        }
        sG[tid] = G;
        Gbuf[(size_t)h * T_LEN + t0 + tid] = G;
    }
    __syncthreads();

    // MFMA: KK (strict lower) and QK (lower incl diag), split bf16
    const char TIa[10] = {0,1,1,2,2,2,3,3,3,3};
    const char TJa[10] = {0,0,1,0,1,2,0,1,2,3};
    const size_t kbase = ((size_t)kh * T_LEN + t0) * DKn;
    for (int idx = wid; idx < 10; idx += 4) {
        const int mi = TIa[idx], nj = TJa[idx];
        f32x4 aKK = {0.f,0.f,0.f,0.f}, aQK = {0.f,0.f,0.f,0.f};
        #pragma unroll
        for (int kk = 0; kk < 4; ++kk) {
            const size_t offA = kbase + (size_t)(16*mi + l15) * DKn + 32*kk + 8*lg;
            const size_t offB = kbase + (size_t)(16*nj + l15) * DKn + 32*kk + 8*lg;
            short8 kAh = *(const short8*)(ksh + offA);
            short8 kAl = *(const short8*)(ksl + offA);
            short8 kBh = *(const short8*)(ksh + offB);
            short8 kBl = *(const short8*)(ksl + offB);
            short8 qAh = *(const short8*)(qsh + offA);
            short8 qAl = *(const short8*)(qsl + offA);
            aKK = MF(kAh,kBh,aKK); aKK = MF(kAh,kBl,aKK); aKK = MF(kAl,kBh,aKK);
            aQK = MF(qAh,kBh,aQK); aQK = MF(qAh,kBl,aQK); aQK = MF(qAl,kBh,aQK);
        }
        #pragma unroll
        for (int r = 0; r < 4; ++r) {
            const int i = 16*mi + 4*lg + r;
            const int j = 16*nj + l15;
            const float e = __expf(fminf(sG[i] - sG[j], 0.f));
            sA[i][j] = (j < i) ? sB[i] * e * aKK[r] : 0.f;
            const float mv = (j <= i) ? e * aQK[r] : 0.f;
            unsigned short mh, ml; bsplit(mv, mh, ml);
            const size_t moff = (((size_t)h * NCH + ch) * CS + i) * CS + j;
            Mh[moff] = mh; Ml[moff] = ml;
        }
    }
    __syncthreads();

    // forward substitution: (I+A) X = RHS; cols 0..127 = U, 128..255 = W
    const int c = tid;
    float X[64];
    if (c < 128) {
        #pragma unroll
        for (int i = 0; i < 64; ++i)
            X[i] = va2[((size_t)h * T_LEN + t0 + i) * DVn + c];
    } else {
        const int dk = c - 128;
        #pragma unroll
        for (int i = 0; i < 64; ++i) {
            const size_t o = ((size_t)kh * T_LEN + t0 + i) * DKn + dk;
            const float kf = bf16tof(ksh[o]) + bf16tof(ksl[o]);
            X[i] = sB[i] * __expf(sG[i]) * kf;
        }
    }
    #pragma unroll
    for (int i = 1; i < 64; ++i) {
        float acc = X[i];
        const int nq = (i + 3) >> 2;
        #pragma unroll
        for (int q = 0; q < nq; ++q) {
            const f32x4 aa = *(const f32x4*)&sA[i][4*q];
            acc = fmaf(-aa[0], X[4*q+0], acc);
            acc = fmaf(-aa[1], X[4*q+1], acc);
            acc = fmaf(-aa[2], X[4*q+2], acc);
            acc = fmaf(-aa[3], X[4*q+3], acc);
        }
        X[i] = acc;
    }
    if (c < 128) {
        #pragma unroll
        for (int i = 0; i < 64; ++i)
            va2[((size_t)h * T_LEN + t0 + i) * DVn + c] = X[i];   // U in place
    } else {
        const int dk = c - 128;
        #pragma unroll
        for (int i = 0; i < 64; ++i) {
            unsigned short wh, wl; bsplit(-X[i], wh, wl);         // store -W
            const size_t o = (((size_t)h * NCH + ch) * CS + i) * DKn + dk;
            Wh[o] = wh; Wl[o] = wl;
        }
    }
}

// ---------------- phase 2: S in registers, packed-LDS exchange, volatile-pinned
//                  prefetch, lgkm-only barriers ----------------
struct ChBuf {
    short8 qh[4], ql[4];
    short8 wh[4], wl[4];
    short8 mh[2], ml[2];
    short8 th[2][2], tl[2][2];
    float  u[4];
    f32x4  g4;
    float  g63;
};

// 34 volatile loads per chunk — issue-pinned as a batch, spill-safe
__device__ __forceinline__ void issue_ch(ChBuf& B, int ch,
    const unsigned short* __restrict__ qsh, const unsigned short* __restrict__ qsl,
    const unsigned short* __restrict__ kth, const unsigned short* __restrict__ ktl,
    const unsigned short* __restrict__ Wh, const unsigned short* __restrict__ Wl,
    const unsigned short* __restrict__ Mh, const unsigned short* __restrict__ Ml,
    const float* __restrict__ va2, const float* __restrict__ Gbuf,
    int h, int kh, int n0, int wid, int l15, int lg)
{
    const int t0 = ch * CS;
    const size_t wbase = (((size_t)h * NCH + ch) * CS + 16*wid + l15) * DKn;
    #pragma unroll
    for (int kk = 0; kk < 4; ++kk) {
        B.wh[kk] = vld16(Wh + wbase + 32*kk + 8*lg);
        B.wl[kk] = vld16(Wl + wbase + 32*kk + 8*lg);
    }
    #pragma unroll
    for (int r = 0; r < 4; ++r)
        B.u[r] = vld4(va2 + ((size_t)h * T_LEN + t0 + 16*wid + 4*lg + r) * DVn + n0 + l15);
    const float* gp = Gbuf + (size_t)h * T_LEN + t0;
    B.g4  = vld16f(gp + 16*wid + 4*lg);
    B.g63 = vld4(gp + 63);
    const size_t kb0 = ((size_t)kh * DKn + 16*wid + l15) * T_LEN + t0;
    const size_t kb1 = ((size_t)kh * DKn + 16*(wid + 4) + l15) * T_LEN + t0;
    #pragma unroll
    for (int k2 = 0; k2 < 2; ++k2) {
        B.th[0][k2] = vld16(kth + kb0 + 32*k2 + 8*lg);
        B.tl[0][k2] = vld16(ktl + kb0 + 32*k2 + 8*lg);
        B.th[1][k2] = vld16(kth + kb1 + 32*k2 + 8*lg);
        B.tl[1][k2] = vld16(ktl + kb1 + 32*k2 + 8*lg);
    }
    const size_t qbase = ((size_t)kh * T_LEN + t0 + 16*wid + l15) * DKn;
    #pragma unroll
    for (int kk = 0; kk < 4; ++kk) {
        B.qh[kk] = vld16(qsh + qbase + 32*kk + 8*lg);
        B.ql[kk] = vld16(qsl + qbase + 32*kk + 8*lg);
    }
    const size_t mbase = (((size_t)h * NCH + ch) * CS + 16*wid + l15) * CS;
    #pragma unroll
    for (int k2 = 0; k2 < 2; ++k2) {
        B.mh[k2] = vld16(Mh + mbase + 32*k2 + 8*lg);
        B.ml[k2] = vld16(Ml + mbase + 32*k2 + 8*lg);
    }
}

__device__ __forceinline__ void compute_ch(const ChBuf& B, int ch,
    unsigned (*sSp)[132], unsigned (*sDLp)[68], unsigned (*sDSp)[68],
    short8* Sbh, short8* Sbl, f32x4* Sc,
    float* __restrict__ out,
    int h, int n0, int wid, int l15, int lg)
{
    const int t0 = ch * CS;
    const float g63 = B.g63;
    const float gr[4] = {B.g4[0], B.g4[1], B.g4[2], B.g4[3]};

    // DL = U + (-W) @ S   (S from registers)
    f32x4 dl;
    #pragma unroll
    for (int r = 0; r < 4; ++r) dl[r] = B.u[r];
    #pragma unroll
    for (int kk = 0; kk < 4; ++kk) {
        dl = MF(B.wh[kk], Sbh[kk], dl); dl = MF(B.wh[kk], Sbl[kk], dl); dl = MF(B.wl[kk], Sbh[kk], dl);
    }

    // write packed DL, DS (= DL * exp(G63 - G_t))
    const int cc0 = 16*wid + 4*lg;
    u32x4 pdl, pds;
    #pragma unroll
    for (int r = 0; r < 4; ++r) {
        pdl[r] = packsplit(dl[r]);
        pds[r] = packsplit(dl[r] * __expf(g63 - gr[r]));
    }
    *(u32x4*)&sDLp[l15][cc0] = pdl;
    *(u32x4*)&sDSp[l15][cc0] = pds;
    BARL();                                  // barrier 1: DL/DS visible (vmem stays in flight)

    // read DL/DS B-frags
    short8 dlh[2], dll[2], dsh[2], dsl[2];
    #pragma unroll
    for (int k2 = 0; k2 < 2; ++k2) {
        u32x4 x0 = *(const u32x4*)&sDLp[l15][32*k2 + 8*lg];
        u32x4 x1 = *(const u32x4*)&sDLp[l15][32*k2 + 8*lg + 4];
        unpack8(x0, x1, dlh[k2], dll[k2]);
        u32x4 y0 = *(const u32x4*)&sDSp[l15][32*k2 + 8*lg];
        u32x4 y1 = *(const u32x4*)&sDSp[l15][32*k2 + 8*lg + 4];
        unpack8(y0, y1, dsh[k2], dsl[k2]);
    }

    // O = exp(G_i)*(Q@S) + M@DL
    f32x4 aq = {0.f,0.f,0.f,0.f}, am = {0.f,0.f,0.f,0.f};
    #pragma unroll
    for (int kk = 0; kk < 4; ++kk) {
        aq = MF(B.qh[kk], Sbh[kk], aq); aq = MF(B.qh[kk], Sbl[kk], aq); aq = MF(B.ql[kk], Sbh[kk], aq);
    }
    #pragma unroll
    for (int k2 = 0; k2 < 2; ++k2) {
        am = MF(B.mh[k2], dlh[k2], am); am = MF(B.mh[k2], dll[k2], am); am = MF(B.ml[k2], dlh[k2], am);
    }
    #pragma unroll
    for (int r = 0; r < 4; ++r) {
        const int cc = cc0 + r;
        out[((size_t)(t0 + cc) * HVn + h) * DVn + n0 + l15] = fmaf(__expf(gr[r]), aq[r], am[r]);
    }

    // S' = lam*S + K^T @ DS  (f32 master in regs), then publish packed split
    const float lam = __expf(g63);
    #pragma unroll
    for (int m2 = 0; m2 < 2; ++m2) {
        f32x4 t4 = {0.f,0.f,0.f,0.f};
        #pragma unroll
        for (int k2 = 0; k2 < 2; ++k2) {
            t4 = MF(B.th[m2][k2], dsh[k2], t4); t4 = MF(B.th[m2][k2], dsl[k2], t4); t4 = MF(B.tl[m2][k2], dsh[k2], t4);
        }
        u32x4 ps;
        #pragma unroll
        for (int r = 0; r < 4; ++r) {
            Sc[m2][r] = fmaf(lam, Sc[m2][r], t4[r]);
            ps[r] = packsplit(Sc[m2][r]);
        }
        *(u32x4*)&sSp[l15][16*wid + 64*m2 + 4*lg] = ps;
    }
    BARL();                                  // barrier 2: S visible (vmem stays in flight)

    // refresh register B-frag copy of S for next chunk
    #pragma unroll
    for (int kk = 0; kk < 4; ++kk) {
        u32x4 z0 = *(const u32x4*)&sSp[l15][32*kk + 8*lg];
        u32x4 z1 = *(const u32x4*)&sSp[l15][32*kk + 8*lg + 4];
        unpack8(z0, z1, Sbh[kk], Sbl[kk]);
    }
}

__global__ __launch_bounds__(256, 1) void k_p2(
    const unsigned short* __restrict__ qsh, const unsigned short* __restrict__ qsl,
    const unsigned short* __restrict__ kth, const unsigned short* __restrict__ ktl,
    const unsigned short* __restrict__ Wh, const unsigned short* __restrict__ Wl,
    const unsigned short* __restrict__ Mh, const unsigned short* __restrict__ Ml,
    const float* __restrict__ va2, const float* __restrict__ Gbuf,
    float* __restrict__ out)
{
    __shared__ unsigned sSp[16][132];    // packed split S, [col][row dk]
    __shared__ unsigned sDLp[16][68];    // packed split DL, [col][row t]
    __shared__ unsigned sDSp[16][68];    // packed split DS

    // XCD co-location: all 8 dv-slices of a head on one XCD; 4 heads per XCD.
    const int p = blockIdx.x;
    const int slot = p >> 3;
    const int h  = (p & 7) * 4 + (slot & 3);   // value head
    const int nb = slot >> 2;                  // dv-slice 0..7
    const int kh = h >> 1, n0 = nb * 16;
    const int tid = threadIdx.x, lane = tid & 63, wid = tid >> 6;
    const int l15 = lane & 15, lg = lane >> 4;

    short8 Sbh[4], Sbl[4];
    f32x4 Sc[2];
    const short8 z8 = {0,0,0,0,0,0,0,0};
    #pragma unroll
    for (int kk = 0; kk < 4; ++kk) { Sbh[kk] = z8; Sbl[kk] = z8; }
    Sc[0] = (f32x4){0.f,0.f,0.f,0.f};
    Sc[1] = (f32x4){0.f,0.f,0.f,0.f};

    ChBuf bufA, bufB;
    issue_ch(bufA, 0, qsh, qsl, kth, ktl, Wh, Wl, Mh, Ml, va2, Gbuf,
             h, kh, n0, wid, l15, lg);

    #pragma unroll 1
    for (int ch2 = 0; ch2 < NCH / 2; ++ch2) {
        const int ch = 2 * ch2;
        issue_ch(bufB, ch + 1, qsh, qsl, kth, ktl, Wh, Wl, Mh, Ml, va2, Gbuf,
                 h, kh, n0, wid, l15, lg);
        compute_ch(bufA, ch, sSp, sDLp, sDSp, Sbh, Sbl, Sc, out, h, n0, wid, l15, lg);
        if (ch + 2 < NCH)
            issue_ch(bufA, ch + 2, qsh, qsl, kth, ktl, Wh, Wl, Mh, Ml, va2, Gbuf,
                     h, kh, n0, wid, l15, lg);
        compute_ch(bufB, ch + 1, sSp, sDLp, sDSp, Sbh, Sbl, Sc, out, h, n0, wid, l15, lg);
    }
}

extern "C" void kernel_launch(void* const* d_in, const int* in_sizes, int n_in,
                              void* d_out, int out_size, void* d_ws, size_t ws_size,
                              hipStream_t stream) {
    const float* mixed_qkv = (const float*)d_in[0];
    const float* a         = (const float*)d_in[1];
    const float* b         = (const float*)d_in[2];
    const float* conv_w    = (const float*)d_in[3];
    const float* dt_bias   = (const float*)d_in[4];
    const float* alog      = (const float*)d_in[5];
    float* out = (float*)d_out;
    char* ws = (char*)d_ws;

    unsigned short* qsh = (unsigned short*)(ws + OFF_QSH);
    unsigned short* qsl = (unsigned short*)(ws + OFF_QSL);
    unsigned short* ksh = (unsigned short*)(ws + OFF_KSH);
    unsigned short* ksl = (unsigned short*)(ws + OFF_KSL);
    unsigned short* kth = (unsigned short*)(ws + OFF_KTH);
    unsigned short* ktl = (unsigned short*)(ws + OFF_KTL);
    float*  va2 = (float*)(ws + OFF_VA);
    float2* gbl = (float2*)(ws + OFF_GBL);
    float*  Gbf = (float*)(ws + OFF_G);
    unsigned short* Wh = (unsigned short*)(ws + OFF_WH);
    unsigned short* Wl = (unsigned short*)(ws + OFF_WL);
    unsigned short* Mh = (unsigned short*)(ws + OFF_MH);
    unsigned short* Ml = (unsigned short*)(ws + OFF_ML);

    k_gate<<<(T_LEN * HVn + 255) / 256, 256, 0, stream>>>(a, b, dt_bias, alog, gbl);

    dim3 cgrid(T_LEN, 64);
    k_conv<<<cgrid, 128, 0, stream>>>(mixed_qkv, conv_w, b, qsh, qsl, ksh, ksl, va2);

    k_tr<<<2048, 256, 0, stream>>>(ksh, ksl, kth, ktl);

    k_p1<<<HVn * NCH, 256, 0, stream>>>(gbl, qsh, qsl, ksh, ksl, va2, Gbf, Wh, Wl, Mh, Ml);

    k_p2<<<HVn * 8, 256, 0, stream>>>(qsh, qsl, kth, ktl, Wh, Wl, Mh, Ml, va2, Gbf, out);
}

// Round 19
// 581.166 us; speedup vs baseline: 1.6411x; 1.6411x over previous
//
#include <hip/hip_runtime.h>

#define T_LEN 4096
#define HKn   16
#define HVn   32
#define DKn   128
#define DVn   128
#define QKVn  8192
#define NCH   64
#define CS    64

typedef __attribute__((ext_vector_type(8))) short short8;
typedef __attribute__((ext_vector_type(4))) float f32x4;
typedef __attribute__((ext_vector_type(4))) unsigned u32x4;

// ---------------- ws byte offsets ----------------
#define OFF_QSH  ((size_t)0)                    // [HK][T][DK] u16
#define OFF_QSL  ((size_t)16777216)
#define OFF_KSH  ((size_t)33554432)
#define OFF_KSL  ((size_t)50331648)
#define OFF_KTH  ((size_t)67108864)             // [HK][DK][T] u16
#define OFF_KTL  ((size_t)83886080)
#define OFF_VA   ((size_t)100663296)            // [HV][T][DV] f32 (beta*v -> U in place)
#define OFF_GBL  ((size_t)167772160)            // [HV][T] float2 (beta, logLam)
#define OFF_G    ((size_t)168820736)            // [HV][T] f32 cumsum G
#define OFF_WH   ((size_t)169345024)            // [HV][NCH][CS][DK] u16 (negated W)
#define OFF_WL   ((size_t)202899456)
#define OFF_MH   ((size_t)236453888)            // [HV][NCH][CS][CS] u16
#define OFF_ML   ((size_t)253231104)
// end ~270MB

// ---------------- helpers ----------------
template <int CTRL>
__device__ __forceinline__ float dpp_add(float x) {
    int v = __builtin_amdgcn_update_dpp(0, __float_as_int(x), CTRL, 0xF, 0xF, true);
    return x + __int_as_float(v);
}
__device__ __forceinline__ float reduce32g(float x) {
    x = dpp_add<0x128>(x); x = dpp_add<0x124>(x);
    x = dpp_add<0x122>(x); x = dpp_add<0x121>(x);
    int v = __builtin_amdgcn_ds_swizzle(__float_as_int(x), 0x401F);
    return x + __int_as_float(v);
}
__device__ __forceinline__ unsigned short bf16rne(float f) {
    unsigned x = __float_as_uint(f);
    return (unsigned short)((x + 0x7FFFu + ((x >> 16) & 1u)) >> 16);
}
__device__ __forceinline__ float bf16tof(unsigned short h) {
    return __uint_as_float(((unsigned)h) << 16);
}
__device__ __forceinline__ void bsplit(float f, unsigned short& h, unsigned short& l) {
    h = bf16rne(f);
    l = bf16rne(f - bf16tof(h));
}
__device__ __forceinline__ unsigned packsplit(float f) {
    unsigned short h, l; bsplit(f, h, l);
    return ((unsigned)h << 16) | (unsigned)l;
}
__device__ __forceinline__ f32x4 MF(short8 a, short8 b, f32x4 c) {
    return __builtin_amdgcn_mfma_f32_16x16x32_bf16(a, b, c, 0, 0, 0);
}
// unpack 8 packed u32 (hi<<16|lo) -> hi short8, lo short8
__device__ __forceinline__ void unpack8(u32x4 x0, u32x4 x1, short8& hi, short8& lo) {
    union { u32x4 u; short8 s; } H, L;
    H.u[0] = __builtin_amdgcn_perm(x0.y, x0.x, 0x07060302u);
    L.u[0] = __builtin_amdgcn_perm(x0.y, x0.x, 0x05040100u);
    H.u[1] = __builtin_amdgcn_perm(x0.w, x0.z, 0x07060302u);
    L.u[1] = __builtin_amdgcn_perm(x0.w, x0.z, 0x05040100u);
    H.u[2] = __builtin_amdgcn_perm(x1.y, x1.x, 0x07060302u);
    L.u[2] = __builtin_amdgcn_perm(x1.y, x1.x, 0x05040100u);
    H.u[3] = __builtin_amdgcn_perm(x1.w, x1.z, 0x07060302u);
    L.u[3] = __builtin_amdgcn_perm(x1.w, x1.z, 0x05040100u);
    hi = H.s; lo = L.s;
}
#define SB0() __builtin_amdgcn_sched_barrier(0)
// raw barrier: drain LDS only; in-flight global loads survive
#define BARL() do { \
    asm volatile("s_waitcnt lgkmcnt(0)" ::: "memory"); \
    __builtin_amdgcn_s_barrier(); \
    asm volatile("" ::: "memory"); \
} while (0)
#define WAITV0() do { \
    asm volatile("s_waitcnt vmcnt(0)" ::: "memory"); \
    SB0(); \
} while (0)
#define WAITL0() do { \
    asm volatile("s_waitcnt lgkmcnt(0)" ::: "memory"); \
    SB0(); \
} while (0)

// ---------------- global->LDS async (R2-proven form) ----------------
typedef __attribute__((address_space(3))) void lds_t;
typedef const __attribute__((address_space(1))) void gbl_t;
__device__ __forceinline__ void load_lds16(const void* g, void* l) {
    __builtin_amdgcn_global_load_lds((gbl_t*)g, (lds_t*)l, 16, 0, 0);
}
__device__ __forceinline__ void load_lds4(const void* g, void* l) {
    __builtin_amdgcn_global_load_lds((gbl_t*)g, (lds_t*)l, 4, 0, 0);
}

// ---------------- prep: gating ----------------
__global__ __launch_bounds__(256) void k_gate(
    const float* __restrict__ a, const float* __restrict__ b,
    const float* __restrict__ dt_bias, const float* __restrict__ alog,
    float2* __restrict__ gbl)
{
    const int i = blockIdx.x * 256 + threadIdx.x;
    if (i < T_LEN * HVn) {
        const int h = i >> 12, t = i & (T_LEN - 1);
        const float av = a[(size_t)t * HVn + h];
        const float bv = b[(size_t)t * HVn + h];
        const float xv = av + dt_bias[h];
        const float sp = fmaxf(xv, 0.f) + log1pf(expf(-fabsf(xv)));
        const float g  = -expf(alog[h]) * sp;          // log lambda
        const float beta = 1.f / (1.f + expf(-bv));
        gbl[(size_t)h * T_LEN + t] = make_float2(beta, g);
    }
}

// ---------------- prep: conv + SiLU + L2norm, bf16-split q/k, beta*v ----------------
__global__ __launch_bounds__(128) void k_conv(
    const float* __restrict__ x, const float* __restrict__ w,
    const float* __restrict__ bgate,
    unsigned short* __restrict__ qsh, unsigned short* __restrict__ qsl,
    unsigned short* __restrict__ ksh, unsigned short* __restrict__ ksl,
    float* __restrict__ va2)
{
    const int t = blockIdx.x, seg = blockIdx.y, d = threadIdx.x;
    const int c = seg * 128 + d;
    const float4 w4 = ((const float4*)w)[c];
    float acc;
    if (t >= 3) {
        const float* xc = x + (size_t)(t - 3) * QKVn + c;
        acc = fmaf(w4.x, xc[0], fmaf(w4.y, xc[(size_t)QKVn],
              fmaf(w4.z, xc[(size_t)2 * QKVn], w4.w * xc[(size_t)3 * QKVn])));
    } else {
        float a0 = (t - 3 >= 0) ? x[(size_t)(t - 3) * QKVn + c] : 0.f;
        float a1 = (t - 2 >= 0) ? x[(size_t)(t - 2) * QKVn + c] : 0.f;
        float a2 = (t - 1 >= 0) ? x[(size_t)(t - 1) * QKVn + c] : 0.f;
        float a3 = x[(size_t)t * QKVn + c];
        acc = fmaf(w4.x, a0, fmaf(w4.y, a1, fmaf(w4.z, a2, w4.w * a3)));
    }
    const float y = acc / (1.f + expf(-acc));

    if (seg < 32) {
        float ss = reduce32g(y * y);
        __shared__ float part[4];
        if ((threadIdx.x & 31) == 0) part[threadIdx.x >> 5] = ss;
        __syncthreads();
        const float total = part[0] + part[1] + part[2] + part[3];
        const float r = rsqrtf(total + 1e-6f);
        float o = y * r;
        unsigned short hh, ll;
        if (seg < 16) {
            o *= 0.08838834764831845f;
            bsplit(o, hh, ll);
            const size_t idx = ((size_t)seg * T_LEN + t) * DKn + d;
            qsh[idx] = hh; qsl[idx] = ll;
        } else {
            bsplit(o, hh, ll);
            const size_t idx = ((size_t)(seg - 16) * T_LEN + t) * DKn + d;
            ksh[idx] = hh; ksl[idx] = ll;
        }
    } else {
        const int h = seg - 32;
        const float bv = bgate[(size_t)t * HVn + h];
        const float beta = 1.f / (1.f + expf(-bv));
        va2[((size_t)h * T_LEN + t) * DVn + d] = y * beta;
    }
}

// ---------------- transpose k -> [HK][DK][T] ----------------
__global__ __launch_bounds__(256) void k_tr(
    const unsigned short* __restrict__ ksh, const unsigned short* __restrict__ ksl,
    unsigned short* __restrict__ kth, unsigned short* __restrict__ ktl)
{
    __shared__ unsigned pk[64][65];
    const int b = blockIdx.x;
    const int kh = b >> 7, tt = (b >> 1) & 63, hh = b & 1;
    const int t0 = tt * 64, d0 = hh * 64;
    const int tid = threadIdx.x;
    #pragma unroll
    for (int e = 0; e < 16; ++e) {
        const int lin = e * 256 + tid;
        const int tl = lin >> 6, dl = lin & 63;
        const size_t o = ((size_t)kh * T_LEN + t0 + tl) * DKn + d0 + dl;
        pk[tl][dl] = ((unsigned)ksh[o] << 16) | (unsigned)ksl[o];
    }
    __syncthreads();
    #pragma unroll
    for (int e = 0; e < 16; ++e) {
        const int lin = e * 256 + tid;
        const int dl = lin >> 6, tl = lin & 63;
        const unsigned v = pk[tl][dl];
        const size_t o = ((size_t)kh * DKn + d0 + dl) * T_LEN + t0 + tl;
        kth[o] = (unsigned short)(v >> 16);
        ktl[o] = (unsigned short)(v & 0xFFFF);
    }
}

// ---------------- phase 1: per (head, chunk): G, A, M, solve -> U (in va2), -W ----------------
__global__ __launch_bounds__(256) void k_p1(
    const float2* __restrict__ gbl,
    const unsigned short* __restrict__ qsh, const unsigned short* __restrict__ qsl,
    const unsigned short* __restrict__ ksh, const unsigned short* __restrict__ ksl,
    float* __restrict__ va2, float* __restrict__ Gbuf,
    unsigned short* __restrict__ Wh, unsigned short* __restrict__ Wl,
    unsigned short* __restrict__ Mh, unsigned short* __restrict__ Ml)
{
    __shared__ float sA[64][68];
    __shared__ float sG[64];
    __shared__ float sB[64];
    const int blk = blockIdx.x;
    const int h = blk >> 6, ch = blk & 63;
    const int kh = h >> 1, t0 = ch * 64;
    const int tid = threadIdx.x, lane = tid & 63, wid = tid >> 6;
    const int l15 = lane & 15, lg = lane >> 4;

    if (tid < 64) {
        float2 g2 = gbl[(size_t)h * T_LEN + t0 + tid];
        sB[tid] = g2.x;
        float G = g2.y;
        #pragma unroll
        for (int s = 1; s < 64; s <<= 1) {
            float y = __int_as_float(__builtin_amdgcn_ds_bpermute((tid - s) << 2, __float_as_int(G)));
            G += (tid >= s) ? y : 0.f;
        }
        sG[tid] = G;
        Gbuf[(size_t)h * T_LEN + t0 + tid] = G;
    }
    __syncthreads();

    // MFMA: KK (strict lower) and QK (lower incl diag), split bf16
    const char TIa[10] = {0,1,1,2,2,2,3,3,3,3};
    const char TJa[10] = {0,0,1,0,1,2,0,1,2,3};
    const size_t kbase = ((size_t)kh * T_LEN + t0) * DKn;
    for (int idx = wid; idx < 10; idx += 4) {
        const int mi = TIa[idx], nj = TJa[idx];
        f32x4 aKK = {0.f,0.f,0.f,0.f}, aQK = {0.f,0.f,0.f,0.f};
        #pragma unroll
        for (int kk = 0; kk < 4; ++kk) {
            const size_t offA = kbase + (size_t)(16*mi + l15) * DKn + 32*kk + 8*lg;
            const size_t offB = kbase + (size_t)(16*nj + l15) * DKn + 32*kk + 8*lg;
            short8 kAh = *(const short8*)(ksh + offA);
            short8 kAl = *(const short8*)(ksl + offA);
            short8 kBh = *(const short8*)(ksh + offB);
            short8 kBl = *(const short8*)(ksl + offB);
            short8 qAh = *(const short8*)(qsh + offA);
            short8 qAl = *(const short8*)(qsl + offA);
            aKK = MF(kAh,kBh,aKK); aKK = MF(kAh,kBl,aKK); aKK = MF(kAl,kBh,aKK);
            aQK = MF(qAh,kBh,aQK); aQK = MF(qAh,kBl,aQK); aQK = MF(qAl,kBh,aQK);
        }
        #pragma unroll
        for (int r = 0; r < 4; ++r) {
            const int i = 16*mi + 4*lg + r;
            const int j = 16*nj + l15;
            const float e = __expf(fminf(sG[i] - sG[j], 0.f));
            sA[i][j] = (j < i) ? sB[i] * e * aKK[r] : 0.f;
            const float mv = (j <= i) ? e * aQK[r] : 0.f;
            unsigned short mh, ml; bsplit(mv, mh, ml);
            const size_t moff = (((size_t)h * NCH + ch) * CS + i) * CS + j;
            Mh[moff] = mh; Ml[moff] = ml;
        }
    }
    __syncthreads();

    // forward substitution: (I+A) X = RHS; cols 0..127 = U, 128..255 = W
    const int c = tid;
    float X[64];
    if (c < 128) {
        #pragma unroll
        for (int i = 0; i < 64; ++i)
            X[i] = va2[((size_t)h * T_LEN + t0 + i) * DVn + c];
    } else {
        const int dk = c - 128;
        #pragma unroll
        for (int i = 0; i < 64; ++i) {
            const size_t o = ((size_t)kh * T_LEN + t0 + i) * DKn + dk;
            const float kf = bf16tof(ksh[o]) + bf16tof(ksl[o]);
            X[i] = sB[i] * __expf(sG[i]) * kf;
        }
    }
    #pragma unroll
    for (int i = 1; i < 64; ++i) {
        float acc = X[i];
        const int nq = (i + 3) >> 2;
        #pragma unroll
        for (int q = 0; q < nq; ++q) {
            const f32x4 aa = *(const f32x4*)&sA[i][4*q];
            acc = fmaf(-aa[0], X[4*q+0], acc);
            acc = fmaf(-aa[1], X[4*q+1], acc);
            acc = fmaf(-aa[2], X[4*q+2], acc);
            acc = fmaf(-aa[3], X[4*q+3], acc);
        }
        X[i] = acc;
    }
    if (c < 128) {
        #pragma unroll
        for (int i = 0; i < 64; ++i)
            va2[((size_t)h * T_LEN + t0 + i) * DVn + c] = X[i];   // U in place
    } else {
        const int dk = c - 128;
        #pragma unroll
        for (int i = 0; i < 64; ++i) {
            unsigned short wh, wl; bsplit(-X[i], wh, wl);         // store -W
            const size_t o = (((size_t)h * NCH + ch) * CS + i) * DKn + dk;
            Wh[o] = wh; Wl[o] = wl;
        }
    }
}

// ---------------- phase 2: per-wave LDS staging via global_load_lds ----------------
// stage layout per wave (bytes): 28 slots x 1024 (16B/lane x 64 lanes) + G row 256 + U 4x256
#define SLOT  1024
#define OFF_GROW 28672
#define OFF_U    28928
#define WSTG  29952

__global__ __launch_bounds__(256, 1) void k_p2(
    const unsigned short* __restrict__ qsh, const unsigned short* __restrict__ qsl,
    const unsigned short* __restrict__ kth, const unsigned short* __restrict__ ktl,
    const unsigned short* __restrict__ Wh, const unsigned short* __restrict__ Wl,
    const unsigned short* __restrict__ Mh, const unsigned short* __restrict__ Ml,
    const float* __restrict__ va2, const float* __restrict__ Gbuf,
    float* __restrict__ out)
{
    __shared__ __align__(16) char stg[4][WSTG];     // per-wave staging
    __shared__ unsigned sSp[16][132];
    __shared__ unsigned sDLp[16][68];
    __shared__ unsigned sDSp[16][68];

    const int p = blockIdx.x;
    const int slot = p >> 3;
    const int h  = (p & 7) * 4 + (slot & 3);   // value head (XCD co-location)
    const int nb = slot >> 2;                  // dv-slice 0..7
    const int kh = h >> 1, n0 = nb * 16;
    const int tid = threadIdx.x, lane = tid & 63, wid = tid >> 6;
    const int l15 = lane & 15, lg = lane >> 4;

    char* wb = &stg[wid][0];

    short8 Sbh[4], Sbl[4];
    f32x4 Sc[2];
    const short8 z8 = {0,0,0,0,0,0,0,0};
    #pragma unroll
    for (int kk = 0; kk < 4; ++kk) { Sbh[kk] = z8; Sbl[kk] = z8; }
    Sc[0] = (f32x4){0.f,0.f,0.f,0.f};
    Sc[1] = (f32x4){0.f,0.f,0.f,0.f};

    // ---- stage chunk ch into this wave's region (33 async loads, 0 VGPR) ----
    auto stage_ch = [&](int ch) {
        const int t0 = ch * CS;
        const size_t wbase = (((size_t)h * NCH + ch) * CS + 16*wid + l15) * DKn + 8*lg;
        #pragma unroll
        for (int kk = 0; kk < 4; ++kk) {
            load_lds16(Wh + wbase + 32*kk, wb + (0 + kk) * SLOT);
            load_lds16(Wl + wbase + 32*kk, wb + (4 + kk) * SLOT);
        }
        const size_t kb0 = ((size_t)kh * DKn + 16*wid + l15) * T_LEN + t0 + 8*lg;
        const size_t kb1 = ((size_t)kh * DKn + 16*(wid + 4) + l15) * T_LEN + t0 + 8*lg;
        #pragma unroll
        for (int k2 = 0; k2 < 2; ++k2) {
            load_lds16(kth + kb0 + 32*k2, wb + (8  + k2) * SLOT);
            load_lds16(kth + kb1 + 32*k2, wb + (10 + k2) * SLOT);
            load_lds16(ktl + kb0 + 32*k2, wb + (12 + k2) * SLOT);
            load_lds16(ktl + kb1 + 32*k2, wb + (14 + k2) * SLOT);
        }
        const size_t qbase = ((size_t)kh * T_LEN + t0 + 16*wid + l15) * DKn + 8*lg;
        #pragma unroll
        for (int kk = 0; kk < 4; ++kk) {
            load_lds16(qsh + qbase + 32*kk, wb + (16 + kk) * SLOT);
            load_lds16(qsl + qbase + 32*kk, wb + (20 + kk) * SLOT);
        }
        const size_t mbase = (((size_t)h * NCH + ch) * CS + 16*wid + l15) * CS + 8*lg;
        #pragma unroll
        for (int k2 = 0; k2 < 2; ++k2) {
            load_lds16(Mh + mbase + 32*k2, wb + (24 + k2) * SLOT);
            load_lds16(Ml + mbase + 32*k2, wb + (26 + k2) * SLOT);
        }
        load_lds4(Gbuf + (size_t)h * T_LEN + t0 + lane, wb + OFF_GROW);
        #pragma unroll
        for (int r = 0; r < 4; ++r)
            load_lds4(va2 + ((size_t)h * T_LEN + t0 + 16*wid + 4*lg + r) * DVn + n0 + l15,
                      wb + OFF_U + r * 256);
    };

    stage_ch(0);

    #pragma unroll 1
    for (int ch = 0; ch < NCH; ++ch) {
        const int t0 = ch * CS;
        WAITV0();                      // staged data landed in LDS

        // scalars from staged G row (broadcast reads)
        const float* gw = (const float*)(wb + OFF_GROW);
        float gr[4];
        #pragma unroll
        for (int r = 0; r < 4; ++r) gr[r] = gw[16*wid + 4*lg + r];
        const float g63 = gw[63];
        const float lam = __expf(g63);
        float scE[4], eg[4];
        #pragma unroll
        for (int r = 0; r < 4; ++r) { scE[r] = __expf(g63 - gr[r]); eg[r] = __expf(gr[r]); }
        float uf[4];
        #pragma unroll
        for (int r = 0; r < 4; ++r) uf[r] = *(const float*)(wb + OFF_U + r * 256 + lane * 4);

        // ---- DL = U + (-W) @ S ----
        f32x4 dl = {uf[0], uf[1], uf[2], uf[3]};
        #pragma unroll
        for (int kk = 0; kk < 4; ++kk) {
            const short8 wh8 = *(const short8*)(wb + (0 + kk) * SLOT + lane * 16);
            const short8 wl8 = *(const short8*)(wb + (4 + kk) * SLOT + lane * 16);
            dl = MF(wh8, Sbh[kk], dl); dl = MF(wh8, Sbl[kk], dl); dl = MF(wl8, Sbh[kk], dl);
        }

        const int cc0 = 16*wid + 4*lg;
        u32x4 pdl, pds;
        #pragma unroll
        for (int r = 0; r < 4; ++r) {
            pdl[r] = packsplit(dl[r]);
            pds[r] = packsplit(dl[r] * scE[r]);
        }
        *(u32x4*)&sDLp[l15][cc0] = pdl;
        *(u32x4*)&sDSp[l15][cc0] = pds;
        BARL();                        // barrier 1: DL/DS visible

        short8 dlh[2], dll[2], dsh[2], dsl[2];
        #pragma unroll
        for (int k2 = 0; k2 < 2; ++k2) {
            u32x4 x0 = *(const u32x4*)&sDLp[l15][32*k2 + 8*lg];
            u32x4 x1 = *(const u32x4*)&sDLp[l15][32*k2 + 8*lg + 4];
            unpack8(x0, x1, dlh[k2], dll[k2]);
            u32x4 y0 = *(const u32x4*)&sDSp[l15][32*k2 + 8*lg];
            u32x4 y1 = *(const u32x4*)&sDSp[l15][32*k2 + 8*lg + 4];
            unpack8(y0, y1, dsh[k2], dsl[k2]);
        }

        // ---- O = exp(G_i)*(Q@S) + M@DL ----
        f32x4 aq = {0.f,0.f,0.f,0.f}, am = {0.f,0.f,0.f,0.f};
        #pragma unroll
        for (int kk = 0; kk < 4; ++kk) {
            const short8 qh8 = *(const short8*)(wb + (16 + kk) * SLOT + lane * 16);
            const short8 ql8 = *(const short8*)(wb + (20 + kk) * SLOT + lane * 16);
            aq = MF(qh8, Sbh[kk], aq); aq = MF(qh8, Sbl[kk], aq); aq = MF(ql8, Sbh[kk], aq);
        }
        #pragma unroll
        for (int k2 = 0; k2 < 2; ++k2) {
            const short8 mh8 = *(const short8*)(wb + (24 + k2) * SLOT + lane * 16);
            const short8 ml8 = *(const short8*)(wb + (26 + k2) * SLOT + lane * 16);
            am = MF(mh8, dlh[k2], am); am = MF(mh8, dll[k2], am); am = MF(ml8, dlh[k2], am);
        }
        #pragma unroll
        for (int r = 0; r < 4; ++r) {
            const int cc = cc0 + r;
            out[((size_t)(t0 + cc) * HVn + h) * DVn + n0 + l15] = fmaf(eg[r], aq[r], am[r]);
        }

        // ---- S' = lam*S + kt^T @ DS ----
        #pragma unroll
        for (int m2 = 0; m2 < 2; ++m2) {
            f32x4 t4 = {0.f,0.f,0.f,0.f};
            #pragma unroll
            for (int k2 = 0; k2 < 2; ++k2) {
                const short8 th8 = *(const short8*)(wb + (8 + 2*m2 + k2) * SLOT + lane * 16);
                const short8 tl8 = *(const short8*)(wb + (12 + 2*m2 + k2) * SLOT + lane * 16);
                t4 = MF(th8, dsh[k2], t4); t4 = MF(th8, dsl[k2], t4); t4 = MF(tl8, dsh[k2], t4);
            }
            u32x4 ps;
            #pragma unroll
            for (int r = 0; r < 4; ++r) {
                Sc[m2][r] = fmaf(lam, Sc[m2][r], t4[r]);
                ps[r] = packsplit(Sc[m2][r]);
            }
            *(u32x4*)&sSp[l15][16*wid + 64*m2 + 4*lg] = ps;
        }
        BARL();                        // barrier 2: S visible

        // refresh register B-frag copy of S
        #pragma unroll
        for (int kk = 0; kk < 4; ++kk) {
            u32x4 z0 = *(const u32x4*)&sSp[l15][32*kk + 8*lg];
            u32x4 z1 = *(const u32x4*)&sSp[l15][32*kk + 8*lg + 4];
            unpack8(z0, z1, Sbh[kk], Sbl[kk]);
        }

        // stage next chunk after all staged-data ds_reads drained
        if (ch + 1 < NCH) {
            WAITL0();
            stage_ch(ch + 1);
        }
    }
}

extern "C" void kernel_launch(void* const* d_in, const int* in_sizes, int n_in,
                              void* d_out, int out_size, void* d_ws, size_t ws_size,
                              hipStream_t stream) {
    const float* mixed_qkv = (const float*)d_in[0];
    const float* a         = (const float*)d_in[1];
    const float* b         = (const float*)d_in[2];
    const float* conv_w    = (const float*)d_in[3];
    const float* dt_bias   = (const float*)d_in[4];
    const float* alog      = (const float*)d_in[5];
    float* out = (float*)d_out;
    char* ws = (char*)d_ws;

    unsigned short* qsh = (unsigned short*)(ws + OFF_QSH);
    unsigned short* qsl = (unsigned short*)(ws + OFF_QSL);
    unsigned short* ksh = (unsigned short*)(ws + OFF_KSH);
    unsigned short* ksl = (unsigned short*)(ws + OFF_KSL);
    unsigned short* kth = (unsigned short*)(ws + OFF_KTH);
    unsigned short* ktl = (unsigned short*)(ws + OFF_KTL);
    float*  va2 = (float*)(ws + OFF_VA);
    float2* gbl = (float2*)(ws + OFF_GBL);
    float*  Gbf = (float*)(ws + OFF_G);
    unsigned short* Wh = (unsigned short*)(ws + OFF_WH);
    unsigned short* Wl = (unsigned short*)(ws + OFF_WL);
    unsigned short* Mh = (unsigned short*)(ws + OFF_MH);
    unsigned short* Ml = (unsigned short*)(ws + OFF_ML);

    k_gate<<<(T_LEN * HVn + 255) / 256, 256, 0, stream>>>(a, b, dt_bias, alog, gbl);

    dim3 cgrid(T_LEN, 64);
    k_conv<<<cgrid, 128, 0, stream>>>(mixed_qkv, conv_w, b, qsh, qsl, ksh, ksl, va2);

    k_tr<<<2048, 256, 0, stream>>>(ksh, ksl, kth, ktl);

    k_p1<<<HVn * NCH, 256, 0, stream>>>(gbl, qsh, qsl, ksh, ksl, va2, Gbf, Wh, Wl, Mh, Ml);

    k_p2<<<HVn * 8, 256, 0, stream>>>(qsh, qsl, kth, ktl, Wh, Wl, Mh, Ml, va2, Gbf, out);
}

// Round 20
// 556.201 us; speedup vs baseline: 1.7147x; 1.0449x over previous
//
#include <hip/hip_runtime.h>

#define T_LEN 4096
#define HKn   16
#define HVn   32
#define DKn   128
#define DVn   128
#define QKVn  8192
#define NCH   64
#define CS    64

typedef __attribute__((ext_vector_type(8))) short short8;
typedef __attribute__((ext_vector_type(4))) float f32x4;
typedef __attribute__((ext_vector_type(4))) unsigned u32x4;
typedef __attribute__((ext_vector_type(4))) unsigned short us4;

// ---------------- ws byte offsets ----------------
#define OFF_QSH  ((size_t)0)                    // [HK][T][DK] u16
#define OFF_QSL  ((size_t)16777216)
#define OFF_KSH  ((size_t)33554432)
#define OFF_KSL  ((size_t)50331648)
#define OFF_KTH  ((size_t)67108864)             // [HK][DK][T] u16
#define OFF_KTL  ((size_t)83886080)
#define OFF_VA   ((size_t)100663296)            // [HV][T][DV] f32 (beta*v -> U in place)
#define OFF_GBL  ((size_t)167772160)            // [HV][T] float2 (beta, logLam)
#define OFF_G    ((size_t)168820736)            // [HV][T] f32 cumsum G
#define OFF_WH   ((size_t)169345024)            // [HV][NCH][CS][DK] u16 (negated W)
#define OFF_WL   ((size_t)202899456)
#define OFF_MH   ((size_t)236453888)            // [HV][NCH][CS][CS] u16
#define OFF_ML   ((size_t)253231104)
// end ~270MB

// ---------------- helpers ----------------
template <int CTRL>
__device__ __forceinline__ float dpp_add(float x) {
    int v = __builtin_amdgcn_update_dpp(0, __float_as_int(x), CTRL, 0xF, 0xF, true);
    return x + __int_as_float(v);
}
__device__ __forceinline__ float reduce32g(float x) {
    x = dpp_add<0x128>(x); x = dpp_add<0x124>(x);
    x = dpp_add<0x122>(x); x = dpp_add<0x121>(x);
    int v = __builtin_amdgcn_ds_swizzle(__float_as_int(x), 0x401F);
    return x + __int_as_float(v);
}
__device__ __forceinline__ unsigned short bf16rne(float f) {
    unsigned x = __float_as_uint(f);
    return (unsigned short)((x + 0x7FFFu + ((x >> 16) & 1u)) >> 16);
}
__device__ __forceinline__ float bf16tof(unsigned short h) {
    return __uint_as_float(((unsigned)h) << 16);
}
__device__ __forceinline__ void bsplit(float f, unsigned short& h, unsigned short& l) {
    h = bf16rne(f);
    l = bf16rne(f - bf16tof(h));
}
__device__ __forceinline__ unsigned packsplit(float f) {
    unsigned short h, l; bsplit(f, h, l);
    return ((unsigned)h << 16) | (unsigned)l;
}
__device__ __forceinline__ f32x4 MF(short8 a, short8 b, f32x4 c) {
    return __builtin_amdgcn_mfma_f32_16x16x32_bf16(a, b, c, 0, 0, 0);
}
__device__ __forceinline__ void unpack8(u32x4 x0, u32x4 x1, short8& hi, short8& lo) {
    union { u32x4 u; short8 s; } H, L;
    H.u[0] = __builtin_amdgcn_perm(x0.y, x0.x, 0x07060302u);
    L.u[0] = __builtin_amdgcn_perm(x0.y, x0.x, 0x05040100u);
    H.u[1] = __builtin_amdgcn_perm(x0.w, x0.z, 0x07060302u);
    L.u[1] = __builtin_amdgcn_perm(x0.w, x0.z, 0x05040100u);
    H.u[2] = __builtin_amdgcn_perm(x1.y, x1.x, 0x07060302u);
    L.u[2] = __builtin_amdgcn_perm(x1.y, x1.x, 0x05040100u);
    H.u[3] = __builtin_amdgcn_perm(x1.w, x1.z, 0x07060302u);
    L.u[3] = __builtin_amdgcn_perm(x1.w, x1.z, 0x05040100u);
    hi = H.s; lo = L.s;
}
#define SB0() __builtin_amdgcn_sched_barrier(0)
#define BARL() do { \
    asm volatile("s_waitcnt lgkmcnt(0)" ::: "memory"); \
    __builtin_amdgcn_s_barrier(); \
    asm volatile("" ::: "memory"); \
} while (0)
#define WAITV0() do { \
    asm volatile("s_waitcnt vmcnt(0)" ::: "memory"); \
    SB0(); \
} while (0)
#define WAITL0() do { \
    asm volatile("s_waitcnt lgkmcnt(0)" ::: "memory"); \
    SB0(); \
} while (0)

// ---------------- global->LDS async ----------------
typedef __attribute__((address_space(3))) void lds_t;
typedef const __attribute__((address_space(1))) void gbl_t;
__device__ __forceinline__ void load_lds16(const void* g, void* l) {
    __builtin_amdgcn_global_load_lds((gbl_t*)g, (lds_t*)l, 16, 0, 0);
}
__device__ __forceinline__ void load_lds4(const void* g, void* l) {
    __builtin_amdgcn_global_load_lds((gbl_t*)g, (lds_t*)l, 4, 0, 0);
}

// ---------------- prep: gating ----------------
__global__ __launch_bounds__(256) void k_gate(
    const float* __restrict__ a, const float* __restrict__ b,
    const float* __restrict__ dt_bias, const float* __restrict__ alog,
    float2* __restrict__ gbl)
{
    const int i = blockIdx.x * 256 + threadIdx.x;
    if (i < T_LEN * HVn) {
        const int h = i >> 12, t = i & (T_LEN - 1);
        const float av = a[(size_t)t * HVn + h];
        const float bv = b[(size_t)t * HVn + h];
        const float xv = av + dt_bias[h];
        const float sp = fmaxf(xv, 0.f) + log1pf(expf(-fabsf(xv)));
        const float g  = -expf(alog[h]) * sp;          // log lambda
        const float beta = 1.f / (1.f + expf(-bv));
        gbl[(size_t)h * T_LEN + t] = make_float2(beta, g);
    }
}

// ---------------- prep: conv + SiLU + L2norm, VECTORIZED 4 ch/thread ----------------
__global__ __launch_bounds__(128) void k_conv(
    const float* __restrict__ x, const float* __restrict__ w,
    const float* __restrict__ bgate,
    unsigned short* __restrict__ qsh, unsigned short* __restrict__ qsl,
    unsigned short* __restrict__ ksh, unsigned short* __restrict__ ksl,
    float* __restrict__ va2)
{
    const int t = blockIdx.x, seg = blockIdx.y, tid = threadIdx.x;
    const int c0 = seg * 512 + tid * 4;

    f32x4 wv[4];
    #pragma unroll
    for (int j = 0; j < 4; ++j) wv[j] = *(const f32x4*)(w + (size_t)(c0 + j) * 4);

    f32x4 acc;
    if (t >= 3) {
        const float* xb = x + (size_t)(t - 3) * QKVn + c0;
        const f32x4 x0 = *(const f32x4*)(xb);
        const f32x4 x1 = *(const f32x4*)(xb + QKVn);
        const f32x4 x2 = *(const f32x4*)(xb + 2 * QKVn);
        const f32x4 x3 = *(const f32x4*)(xb + 3 * QKVn);
        #pragma unroll
        for (int j = 0; j < 4; ++j)
            acc[j] = fmaf(wv[j][0], x0[j], fmaf(wv[j][1], x1[j],
                     fmaf(wv[j][2], x2[j], wv[j][3] * x3[j])));
    } else {
        f32x4 xs[4];
        #pragma unroll
        for (int p = 0; p < 4; ++p) {
            const int tt = t - 3 + p;
            if (tt >= 0) xs[p] = *(const f32x4*)(x + (size_t)tt * QKVn + c0);
            else         xs[p] = (f32x4){0.f, 0.f, 0.f, 0.f};
        }
        #pragma unroll
        for (int j = 0; j < 4; ++j)
            acc[j] = fmaf(wv[j][0], xs[0][j], fmaf(wv[j][1], xs[1][j],
                     fmaf(wv[j][2], xs[2][j], wv[j][3] * xs[3][j])));
    }
    f32x4 y;
    #pragma unroll
    for (int j = 0; j < 4; ++j) y[j] = acc[j] / (1.f + expf(-acc[j]));

    if (seg < 8) {
        // q (seg<4) or k: each 32-lane group = one head of 128 ch
        float ss = y[0]*y[0] + y[1]*y[1] + y[2]*y[2] + y[3]*y[3];
        ss = reduce32g(ss);
        float r = rsqrtf(ss + 1e-6f);
        if (seg < 4) r *= 0.08838834764831845f;        // DK^-0.5 for q
        us4 hi, lo;
        #pragma unroll
        for (int j = 0; j < 4; ++j) {
            unsigned short hh, ll; bsplit(y[j] * r, hh, ll);
            hi[j] = hh; lo[j] = ll;
        }
        const int d = c0 & 127;
        if (seg < 4) {
            const int head = c0 >> 7;
            const size_t idx = ((size_t)head * T_LEN + t) * DKn + d;
            *(us4*)(qsh + idx) = hi; *(us4*)(qsl + idx) = lo;
        } else {
            const int head = (c0 - 2048) >> 7;
            const size_t idx = ((size_t)head * T_LEN + t) * DKn + d;
            *(us4*)(ksh + idx) = hi; *(us4*)(ksl + idx) = lo;
        }
    } else {
        const int h = (c0 - 4096) >> 7;
        const float bv = bgate[(size_t)t * HVn + h];
        const float beta = 1.f / (1.f + expf(-bv));
        f32x4 o;
        #pragma unroll
        for (int j = 0; j < 4; ++j) o[j] = y[j] * beta;
        *(f32x4*)(va2 + ((size_t)h * T_LEN + t) * DVn + (c0 & 127)) = o;
    }
}

// ---------------- transpose k -> [HK][DK][T] ----------------
__global__ __launch_bounds__(256) void k_tr(
    const unsigned short* __restrict__ ksh, const unsigned short* __restrict__ ksl,
    unsigned short* __restrict__ kth, unsigned short* __restrict__ ktl)
{
    __shared__ unsigned pk[64][65];
    const int b = blockIdx.x;
    const int kh = b >> 7, tt = (b >> 1) & 63, hh = b & 1;
    const int t0 = tt * 64, d0 = hh * 64;
    const int tid = threadIdx.x;
    #pragma unroll
    for (int e = 0; e < 16; ++e) {
        const int lin = e * 256 + tid;
        const int tl = lin >> 6, dl = lin & 63;
        const size_t o = ((size_t)kh * T_LEN + t0 + tl) * DKn + d0 + dl;
        pk[tl][dl] = ((unsigned)ksh[o] << 16) | (unsigned)ksl[o];
    }
    __syncthreads();
    #pragma unroll
    for (int e = 0; e < 16; ++e) {
        const int lin = e * 256 + tid;
        const int dl = lin >> 6, tl = lin & 63;
        const unsigned v = pk[tl][dl];
        const size_t o = ((size_t)kh * DKn + d0 + dl) * T_LEN + t0 + tl;
        kth[o] = (unsigned short)(v >> 16);
        ktl[o] = (unsigned short)(v & 0xFFFF);
    }
}

// ---------------- phase 1: per (head, chunk): G, A, M, solve -> U (in va2), -W ----------------
__global__ __launch_bounds__(256) void k_p1(
    const float2* __restrict__ gbl,
    const unsigned short* __restrict__ qsh, const unsigned short* __restrict__ qsl,
    const unsigned short* __restrict__ ksh, const unsigned short* __restrict__ ksl,
    float* __restrict__ va2, float* __restrict__ Gbuf,
    unsigned short* __restrict__ Wh, unsigned short* __restrict__ Wl,
    unsigned short* __restrict__ Mh, unsigned short* __restrict__ Ml)
{
    __shared__ float sA[64][68];
    __shared__ float sG[64];
    __shared__ float sB[64];
    const int blk = blockIdx.x;
    const int h = blk >> 6, ch = blk & 63;
    const int kh = h >> 1, t0 = ch * 64;
    const int tid = threadIdx.x, lane = tid & 63, wid = tid >> 6;
    const int l15 = lane & 15, lg = lane >> 4;

    if (tid < 64) {
        float2 g2 = gbl[(size_t)h * T_LEN + t0 + tid];
        sB[tid] = g2.x;
        float G = g2.y;
        #pragma unroll
        for (int s = 1; s < 64; s <<= 1) {
            float y = __int_as_float(__builtin_amdgcn_ds_bpermute((tid - s) << 2, __float_as_int(G)));
            G += (tid >= s) ? y : 0.f;
        }
        sG[tid] = G;
        Gbuf[(size_t)h * T_LEN + t0 + tid] = G;
    }
    __syncthreads();

    const char TIa[10] = {0,1,1,2,2,2,3,3,3,3};
    const char TJa[10] = {0,0,1,0,1,2,0,1,2,3};
    const size_t kbase = ((size_t)kh * T_LEN + t0) * DKn;
    for (int idx = wid; idx < 10; idx += 4) {
        const int mi = TIa[idx], nj = TJa[idx];
        f32x4 aKK = {0.f,0.f,0.f,0.f}, aQK = {0.f,0.f,0.f,0.f};
        #pragma unroll
        for (int kk = 0; kk < 4; ++kk) {
            const size_t offA = kbase + (size_t)(16*mi + l15) * DKn + 32*kk + 8*lg;
            const size_t offB = kbase + (size_t)(16*nj + l15) * DKn + 32*kk + 8*lg;
            short8 kAh = *(const short8*)(ksh + offA);
            short8 kAl = *(const short8*)(ksl + offA);
            short8 kBh = *(const short8*)(ksh + offB);
            short8 kBl = *(const short8*)(ksl + offB);
            short8 qAh = *(const short8*)(qsh + offA);
            short8 qAl = *(const short8*)(qsl + offA);
            aKK = MF(kAh,kBh,aKK); aKK = MF(kAh,kBl,aKK); aKK = MF(kAl,kBh,aKK);
            aQK = MF(qAh,kBh,aQK); aQK = MF(qAh,kBl,aQK); aQK = MF(qAl,kBh,aQK);
        }
        #pragma unroll
        for (int r = 0; r < 4; ++r) {
            const int i = 16*mi + 4*lg + r;
            const int j = 16*nj + l15;
            const float e = __expf(fminf(sG[i] - sG[j], 0.f));
            sA[i][j] = (j < i) ? sB[i] * e * aKK[r] : 0.f;
            const float mv = (j <= i) ? e * aQK[r] : 0.f;
            unsigned short mh, ml; bsplit(mv, mh, ml);
            const size_t moff = (((size_t)h * NCH + ch) * CS + i) * CS + j;
            Mh[moff] = mh; Ml[moff] = ml;
        }
    }
    __syncthreads();

    const int c = tid;
    float X[64];
    if (c < 128) {
        #pragma unroll
        for (int i = 0; i < 64; ++i)
            X[i] = va2[((size_t)h * T_LEN + t0 + i) * DVn + c];
    } else {
        const int dk = c - 128;
        #pragma unroll
        for (int i = 0; i < 64; ++i) {
            const size_t o = ((size_t)kh * T_LEN + t0 + i) * DKn + dk;
            const float kf = bf16tof(ksh[o]) + bf16tof(ksl[o]);
            X[i] = sB[i] * __expf(sG[i]) * kf;
        }
    }
    #pragma unroll
    for (int i = 1; i < 64; ++i) {
        float acc = X[i];
        const int nq = (i + 3) >> 2;
        #pragma unroll
        for (int q = 0; q < nq; ++q) {
            const f32x4 aa = *(const f32x4*)&sA[i][4*q];
            acc = fmaf(-aa[0], X[4*q+0], acc);
            acc = fmaf(-aa[1], X[4*q+1], acc);
            acc = fmaf(-aa[2], X[4*q+2], acc);
            acc = fmaf(-aa[3], X[4*q+3], acc);
        }
        X[i] = acc;
    }
    if (c < 128) {
        #pragma unroll
        for (int i = 0; i < 64; ++i)
            va2[((size_t)h * T_LEN + t0 + i) * DVn + c] = X[i];   // U in place
    } else {
        const int dk = c - 128;
        #pragma unroll
        for (int i = 0; i < 64; ++i) {
            unsigned short wh, wl; bsplit(-X[i], wh, wl);         // store -W
            const size_t o = (((size_t)h * NCH + ch) * CS + i) * DKn + dk;
            Wh[o] = wh; Wl[o] = wl;
        }
    }
}

// ---------------- phase 2: LDS staging, S-critical-path-first ordering ----------------
#define SLOT  1024
#define OFF_GROW 28672
#define OFF_U    28928
#define WSTG  29952

__global__ __launch_bounds__(256, 1) void k_p2(
    const unsigned short* __restrict__ qsh, const unsigned short* __restrict__ qsl,
    const unsigned short* __restrict__ kth, const unsigned short* __restrict__ ktl,
    const unsigned short* __restrict__ Wh, const unsigned short* __restrict__ Wl,
    const unsigned short* __restrict__ Mh, const unsigned short* __restrict__ Ml,
    const float* __restrict__ va2, const float* __restrict__ Gbuf,
    float* __restrict__ out)
{
    __shared__ __align__(16) char stg[4][WSTG];
    __shared__ unsigned sSp[16][132];
    __shared__ unsigned sDLp[16][68];
    __shared__ unsigned sDSp[16][68];

    const int p = blockIdx.x;
    const int slot = p >> 3;
    const int h  = (p & 7) * 4 + (slot & 3);
    const int nb = slot >> 2;
    const int kh = h >> 1, n0 = nb * 16;
    const int tid = threadIdx.x, lane = tid & 63, wid = tid >> 6;
    const int l15 = lane & 15, lg = lane >> 4;

    char* wb = &stg[wid][0];

    short8 Sbh[4], Sbl[4];
    f32x4 Sc[2];
    const short8 z8 = {0,0,0,0,0,0,0,0};
    #pragma unroll
    for (int kk = 0; kk < 4; ++kk) { Sbh[kk] = z8; Sbl[kk] = z8; }
    Sc[0] = (f32x4){0.f,0.f,0.f,0.f};
    Sc[1] = (f32x4){0.f,0.f,0.f,0.f};

    auto stage_ch = [&](int ch) {
        const int t0 = ch * CS;
        const size_t wbase = (((size_t)h * NCH + ch) * CS + 16*wid + l15) * DKn + 8*lg;
        #pragma unroll
        for (int kk = 0; kk < 4; ++kk) {
            load_lds16(Wh + wbase + 32*kk, wb + (0 + kk) * SLOT);
            load_lds16(Wl + wbase + 32*kk, wb + (4 + kk) * SLOT);
        }
        const size_t kb0 = ((size_t)kh * DKn + 16*wid + l15) * T_LEN + t0 + 8*lg;
        const size_t kb1 = ((size_t)kh * DKn + 16*(wid + 4) + l15) * T_LEN + t0 + 8*lg;
        #pragma unroll
        for (int k2 = 0; k2 < 2; ++k2) {
            load_lds16(kth + kb0 + 32*k2, wb + (8  + k2) * SLOT);
            load_lds16(kth + kb1 + 32*k2, wb + (10 + k2) * SLOT);
            load_lds16(ktl + kb0 + 32*k2, wb + (12 + k2) * SLOT);
            load_lds16(ktl + kb1 + 32*k2, wb + (14 + k2) * SLOT);
        }
        const size_t qbase = ((size_t)kh * T_LEN + t0 + 16*wid + l15) * DKn + 8*lg;
        #pragma unroll
        for (int kk = 0; kk < 4; ++kk) {
            load_lds16(qsh + qbase + 32*kk, wb + (16 + kk) * SLOT);
            load_lds16(qsl + qbase + 32*kk, wb + (20 + kk) * SLOT);
        }
        const size_t mbase = (((size_t)h * NCH + ch) * CS + 16*wid + l15) * CS + 8*lg;
        #pragma unroll
        for (int k2 = 0; k2 < 2; ++k2) {
            load_lds16(Mh + mbase + 32*k2, wb + (24 + k2) * SLOT);
            load_lds16(Ml + mbase + 32*k2, wb + (26 + k2) * SLOT);
        }
        load_lds4(Gbuf + (size_t)h * T_LEN + t0 + lane, wb + OFF_GROW);
        #pragma unroll
        for (int r = 0; r < 4; ++r)
            load_lds4(va2 + ((size_t)h * T_LEN + t0 + 16*wid + 4*lg + r) * DVn + n0 + l15,
                      wb + OFF_U + r * 256);
    };

    stage_ch(0);

    #pragma unroll 1
    for (int ch = 0; ch < NCH; ++ch) {
        const int t0 = ch * CS;
        WAITV0();                      // staged data landed

        const float* gw = (const float*)(wb + OFF_GROW);
        float gr[4];
        #pragma unroll
        for (int r = 0; r < 4; ++r) gr[r] = gw[16*wid + 4*lg + r];
        const float g63 = gw[63];
        const float lam = __expf(g63);
        float scE[4], eg[4];
        #pragma unroll
        for (int r = 0; r < 4; ++r) { scE[r] = __expf(g63 - gr[r]); eg[r] = __expf(gr[r]); }
        float uf[4];
        #pragma unroll
        for (int r = 0; r < 4; ++r) uf[r] = *(const float*)(wb + OFF_U + r * 256 + lane * 4);

        // ---- DL = U + (-W) @ S : 3 independent chains ----
        f32x4 d0 = {uf[0], uf[1], uf[2], uf[3]};
        f32x4 d1 = {0.f,0.f,0.f,0.f}, d2 = {0.f,0.f,0.f,0.f};
        #pragma unroll
        for (int kk = 0; kk < 4; ++kk) {
            const short8 wh8 = *(const short8*)(wb + (0 + kk) * SLOT + lane * 16);
            const short8 wl8 = *(const short8*)(wb + (4 + kk) * SLOT + lane * 16);
            d0 = MF(wh8, Sbh[kk], d0);
            d1 = MF(wh8, Sbl[kk], d1);
            d2 = MF(wl8, Sbh[kk], d2);
        }
        f32x4 dl;
        #pragma unroll
        for (int r = 0; r < 4; ++r) dl[r] = d0[r] + d1[r] + d2[r];

        const int cc0 = 16*wid + 4*lg;
        u32x4 pdl, pds;
        #pragma unroll
        for (int r = 0; r < 4; ++r) {
            pdl[r] = packsplit(dl[r]);
            pds[r] = packsplit(dl[r] * scE[r]);
        }
        *(u32x4*)&sDLp[l15][cc0] = pdl;
        *(u32x4*)&sDSp[l15][cc0] = pds;
        BARL();                        // barrier 1: DL/DS visible

        short8 dlh[2], dll[2], dsh[2], dsl[2];
        #pragma unroll
        for (int k2 = 0; k2 < 2; ++k2) {
            u32x4 x0 = *(const u32x4*)&sDLp[l15][32*k2 + 8*lg];
            u32x4 x1 = *(const u32x4*)&sDLp[l15][32*k2 + 8*lg + 4];
            unpack8(x0, x1, dlh[k2], dll[k2]);
            u32x4 y0 = *(const u32x4*)&sDSp[l15][32*k2 + 8*lg];
            u32x4 y1 = *(const u32x4*)&sDSp[l15][32*k2 + 8*lg + 4];
            unpack8(y0, y1, dsh[k2], dsl[k2]);
        }

        // ---- S' = lam*S + kt^T @ DS  (critical path; 3 chains per m2) ----
        #pragma unroll
        for (int m2 = 0; m2 < 2; ++m2) {
            f32x4 t0a = {0.f,0.f,0.f,0.f}, t1a = {0.f,0.f,0.f,0.f}, t2a = {0.f,0.f,0.f,0.f};
            #pragma unroll
            for (int k2 = 0; k2 < 2; ++k2) {
                const short8 th8 = *(const short8*)(wb + (8 + 2*m2 + k2) * SLOT + lane * 16);
                const short8 tl8 = *(const short8*)(wb + (12 + 2*m2 + k2) * SLOT + lane * 16);
                t0a = MF(th8, dsh[k2], t0a);
                t1a = MF(th8, dsl[k2], t1a);
                t2a = MF(tl8, dsh[k2], t2a);
            }
            u32x4 ps;
            #pragma unroll
            for (int r = 0; r < 4; ++r) {
                Sc[m2][r] = fmaf(lam, Sc[m2][r], t0a[r] + t1a[r] + t2a[r]);
                ps[r] = packsplit(Sc[m2][r]);
            }
            *(u32x4*)&sSp[l15][16*wid + 64*m2 + 4*lg] = ps;
        }
        BARL();                        // barrier 2: S visible

        // ---- O = exp(G_i)*(Q@S_old) + M@DL  (off critical path; uses OLD Sb) ----
        f32x4 aq = {0.f,0.f,0.f,0.f}, am = {0.f,0.f,0.f,0.f};
        #pragma unroll
        for (int kk = 0; kk < 4; ++kk) {
            const short8 qh8 = *(const short8*)(wb + (16 + kk) * SLOT + lane * 16);
            const short8 ql8 = *(const short8*)(wb + (20 + kk) * SLOT + lane * 16);
            aq = MF(qh8, Sbh[kk], aq); aq = MF(qh8, Sbl[kk], aq); aq = MF(ql8, Sbh[kk], aq);
        }
        #pragma unroll
        for (int k2 = 0; k2 < 2; ++k2) {
            const short8 mh8 = *(const short8*)(wb + (24 + k2) * SLOT + lane * 16);
            const short8 ml8 = *(const short8*)(wb + (26 + k2) * SLOT + lane * 16);
            am = MF(mh8, dlh[k2], am); am = MF(mh8, dll[k2], am); am = MF(ml8, dlh[k2], am);
        }
        #pragma unroll
        for (int r = 0; r < 4; ++r) {
            const int cc = cc0 + r;
            out[((size_t)(t0 + cc) * HVn + h) * DVn + n0 + l15] = fmaf(eg[r], aq[r], am[r]);
        }

        // stage next chunk (stg reads retired after drain; refresh reads sSp: disjoint)
        if (ch + 1 < NCH) {
            WAITL0();
            stage_ch(ch + 1);
        }

        // refresh register B-frag copy of S (overlaps the in-flight stage)
        #pragma unroll
        for (int kk = 0; kk < 4; ++kk) {
            u32x4 z0 = *(const u32x4*)&sSp[l15][32*kk + 8*lg];
            u32x4 z1 = *(const u32x4*)&sSp[l15][32*kk + 8*lg + 4];
            unpack8(z0, z1, Sbh[kk], Sbl[kk]);
        }
    }
}

extern "C" void kernel_launch(void* const* d_in, const int* in_sizes, int n_in,
                              void* d_out, int out_size, void* d_ws, size_t ws_size,
                              hipStream_t stream) {
    const float* mixed_qkv = (const float*)d_in[0];
    const float* a         = (const float*)d_in[1];
    const float* b         = (const float*)d_in[2];
    const float* conv_w    = (const float*)d_in[3];
    const float* dt_bias   = (const float*)d_in[4];
    const float* alog      = (const float*)d_in[5];
    float* out = (float*)d_out;
    char* ws = (char*)d_ws;

    unsigned short* qsh = (unsigned short*)(ws + OFF_QSH);
    unsigned short* qsl = (unsigned short*)(ws + OFF_QSL);
    unsigned short* ksh = (unsigned short*)(ws + OFF_KSH);
    unsigned short* ksl = (unsigned short*)(ws + OFF_KSL);
    unsigned short* kth = (unsigned short*)(ws + OFF_KTH);
    unsigned short* ktl = (unsigned short*)(ws + OFF_KTL);
    float*  va2 = (float*)(ws + OFF_VA);
    float2* gbl = (float2*)(ws + OFF_GBL);
    float*  Gbf = (float*)(ws + OFF_G);
    unsigned short* Wh = (unsigned short*)(ws + OFF_WH);
    unsigned short* Wl = (unsigned short*)(ws + OFF_WL);
    unsigned short* Mh = (unsigned short*)(ws + OFF_MH);
    unsigned short* Ml = (unsigned short*)(ws + OFF_ML);

    k_gate<<<(T_LEN * HVn + 255) / 256, 256, 0, stream>>>(a, b, dt_bias, alog, gbl);

    dim3 cgrid(T_LEN, 16);
    k_conv<<<cgrid, 128, 0, stream>>>(mixed_qkv, conv_w, b, qsh, qsl, ksh, ksl, va2);

    k_tr<<<2048, 256, 0, stream>>>(ksh, ksl, kth, ktl);

    k_p1<<<HVn * NCH, 256, 0, stream>>>(gbl, qsh, qsl, ksh, ksl, va2, Gbf, Wh, Wl, Mh, Ml);

    k_p2<<<HVn * 8, 256, 0, stream>>>(qsh, qsl, kth, ktl, Wh, Wl, Mh, Ml, va2, Gbf, out);
}

// Round 21
// 508.135 us; speedup vs baseline: 1.8769x; 1.0946x over previous
//
#include <hip/hip_runtime.h>

#define T_LEN 4096
#define HKn   16
#define HVn   32
#define DKn   128
#define DVn   128
#define QKVn  8192
#define NCH   64
#define CS    64

typedef __attribute__((ext_vector_type(8))) short short8;
typedef __attribute__((ext_vector_type(4))) float f32x4;
typedef __attribute__((ext_vector_type(4))) unsigned u32x4;
typedef __attribute__((ext_vector_type(4))) unsigned short us4;

// ---------------- ws byte offsets ----------------
#define OFF_QSH  ((size_t)0)                    // [HK][T][DK] u16
#define OFF_QSL  ((size_t)16777216)
#define OFF_KSH  ((size_t)33554432)
#define OFF_KSL  ((size_t)50331648)
#define OFF_KTH  ((size_t)67108864)             // [HK][DK][T] u16
#define OFF_KTL  ((size_t)83886080)
#define OFF_VA   ((size_t)100663296)            // [HV][T][DV] f32 (beta*v -> U in place)
#define OFF_GBL  ((size_t)167772160)            // [HV][T] float2 (beta, logLam)
#define OFF_G    ((size_t)168820736)            // [HV][T] f32 cumsum G
#define OFF_WH   ((size_t)169345024)            // [HV][NCH][CS][DK] u16 (negated W)
#define OFF_WL   ((size_t)202899456)
#define OFF_MH   ((size_t)236453888)            // [HV][NCH][CS][CS] u16
#define OFF_ML   ((size_t)253231104)
// end ~270MB

// ---------------- helpers ----------------
template <int CTRL>
__device__ __forceinline__ float dpp_add(float x) {
    int v = __builtin_amdgcn_update_dpp(0, __float_as_int(x), CTRL, 0xF, 0xF, true);
    return x + __int_as_float(v);
}
__device__ __forceinline__ float reduce32g(float x) {
    x = dpp_add<0x128>(x); x = dpp_add<0x124>(x);
    x = dpp_add<0x122>(x); x = dpp_add<0x121>(x);
    int v = __builtin_amdgcn_ds_swizzle(__float_as_int(x), 0x401F);
    return x + __int_as_float(v);
}
__device__ __forceinline__ unsigned short bf16rne(float f) {
    unsigned x = __float_as_uint(f);
    return (unsigned short)((x + 0x7FFFu + ((x >> 16) & 1u)) >> 16);
}
__device__ __forceinline__ float bf16tof(unsigned short h) {
    return __uint_as_float(((unsigned)h) << 16);
}
__device__ __forceinline__ void bsplit(float f, unsigned short& h, unsigned short& l) {
    h = bf16rne(f);
    l = bf16rne(f - bf16tof(h));
}
__device__ __forceinline__ unsigned packsplit(float f) {
    unsigned short h, l; bsplit(f, h, l);
    return ((unsigned)h << 16) | (unsigned)l;
}
__device__ __forceinline__ f32x4 MF(short8 a, short8 b, f32x4 c) {
    return __builtin_amdgcn_mfma_f32_16x16x32_bf16(a, b, c, 0, 0, 0);
}
// unpack 8 packed u32 (hi<<16|lo) -> hi short8, lo short8
__device__ __forceinline__ void unpack8(u32x4 x0, u32x4 x1, short8& hi, short8& lo) {
    union { u32x4 u; short8 s; } H, L;
    H.u[0] = __builtin_amdgcn_perm(x0.y, x0.x, 0x07060302u);
    L.u[0] = __builtin_amdgcn_perm(x0.y, x0.x, 0x05040100u);
    H.u[1] = __builtin_amdgcn_perm(x0.w, x0.z, 0x07060302u);
    L.u[1] = __builtin_amdgcn_perm(x0.w, x0.z, 0x05040100u);
    H.u[2] = __builtin_amdgcn_perm(x1.y, x1.x, 0x07060302u);
    L.u[2] = __builtin_amdgcn_perm(x1.y, x1.x, 0x05040100u);
    H.u[3] = __builtin_amdgcn_perm(x1.w, x1.z, 0x07060302u);
    L.u[3] = __builtin_amdgcn_perm(x1.w, x1.z, 0x05040100u);
    hi = H.s; lo = L.s;
}
#define SB0() __builtin_amdgcn_sched_barrier(0)
// raw barrier: drain LDS only; in-flight global loads survive
#define BARL() do { \
    asm volatile("s_waitcnt lgkmcnt(0)" ::: "memory"); \
    __builtin_amdgcn_s_barrier(); \
    asm volatile("" ::: "memory"); \
} while (0)

// ---------------- prep: gating ----------------
__global__ __launch_bounds__(256) void k_gate(
    const float* __restrict__ a, const float* __restrict__ b,
    const float* __restrict__ dt_bias, const float* __restrict__ alog,
    float2* __restrict__ gbl)
{
    const int i = blockIdx.x * 256 + threadIdx.x;
    if (i < T_LEN * HVn) {
        const int h = i >> 12, t = i & (T_LEN - 1);
        const float av = a[(size_t)t * HVn + h];
        const float bv = b[(size_t)t * HVn + h];
        const float xv = av + dt_bias[h];
        const float sp = fmaxf(xv, 0.f) + log1pf(expf(-fabsf(xv)));
        const float g  = -expf(alog[h]) * sp;          // log lambda
        const float beta = 1.f / (1.f + expf(-bv));
        gbl[(size_t)h * T_LEN + t] = make_float2(beta, g);
    }
}

// ---------------- prep: conv + SiLU + L2norm, VECTORIZED 4 ch/thread ----------------
__global__ __launch_bounds__(128) void k_conv(
    const float* __restrict__ x, const float* __restrict__ w,
    const float* __restrict__ bgate,
    unsigned short* __restrict__ qsh, unsigned short* __restrict__ qsl,
    unsigned short* __restrict__ ksh, unsigned short* __restrict__ ksl,
    float* __restrict__ va2)
{
    const int t = blockIdx.x, seg = blockIdx.y, tid = threadIdx.x;
    const int c0 = seg * 512 + tid * 4;

    f32x4 wv[4];
    #pragma unroll
    for (int j = 0; j < 4; ++j) wv[j] = *(const f32x4*)(w + (size_t)(c0 + j) * 4);

    f32x4 acc;
    if (t >= 3) {
        const float* xb = x + (size_t)(t - 3) * QKVn + c0;
        const f32x4 x0 = *(const f32x4*)(xb);
        const f32x4 x1 = *(const f32x4*)(xb + QKVn);
        const f32x4 x2 = *(const f32x4*)(xb + 2 * QKVn);
        const f32x4 x3 = *(const f32x4*)(xb + 3 * QKVn);
        #pragma unroll
        for (int j = 0; j < 4; ++j)
            acc[j] = fmaf(wv[j][0], x0[j], fmaf(wv[j][1], x1[j],
                     fmaf(wv[j][2], x2[j], wv[j][3] * x3[j])));
    } else {
        f32x4 xs[4];
        #pragma unroll
        for (int p = 0; p < 4; ++p) {
            const int tt = t - 3 + p;
            if (tt >= 0) xs[p] = *(const f32x4*)(x + (size_t)tt * QKVn + c0);
            else         xs[p] = (f32x4){0.f, 0.f, 0.f, 0.f};
        }
        #pragma unroll
        for (int j = 0; j < 4; ++j)
            acc[j] = fmaf(wv[j][0], xs[0][j], fmaf(wv[j][1], xs[1][j],
                     fmaf(wv[j][2], xs[2][j], wv[j][3] * xs[3][j])));
    }
    f32x4 y;
    #pragma unroll
    for (int j = 0; j < 4; ++j) y[j] = acc[j] / (1.f + expf(-acc[j]));

    if (seg < 8) {
        // q (seg<4) or k: each 32-lane group = one head of 128 ch
        float ss = y[0]*y[0] + y[1]*y[1] + y[2]*y[2] + y[3]*y[3];
        ss = reduce32g(ss);
        float r = rsqrtf(ss + 1e-6f);
        if (seg < 4) r *= 0.08838834764831845f;        // DK^-0.5 for q
        us4 hi, lo;
        #pragma unroll
        for (int j = 0; j < 4; ++j) {
            unsigned short hh, ll; bsplit(y[j] * r, hh, ll);
            hi[j] = hh; lo[j] = ll;
        }
        const int d = c0 & 127;
        if (seg < 4) {
            const int head = c0 >> 7;
            const size_t idx = ((size_t)head * T_LEN + t) * DKn + d;
            *(us4*)(qsh + idx) = hi; *(us4*)(qsl + idx) = lo;
        } else {
            const int head = (c0 - 2048) >> 7;
            const size_t idx = ((size_t)head * T_LEN + t) * DKn + d;
            *(us4*)(ksh + idx) = hi; *(us4*)(ksl + idx) = lo;
        }
    } else {
        const int h = (c0 - 4096) >> 7;
        const float bv = bgate[(size_t)t * HVn + h];
        const float beta = 1.f / (1.f + expf(-bv));
        f32x4 o;
        #pragma unroll
        for (int j = 0; j < 4; ++j) o[j] = y[j] * beta;
        *(f32x4*)(va2 + ((size_t)h * T_LEN + t) * DVn + (c0 & 127)) = o;
    }
}

// ---------------- transpose k -> [HK][DK][T] ----------------
__global__ __launch_bounds__(256) void k_tr(
    const unsigned short* __restrict__ ksh, const unsigned short* __restrict__ ksl,
    unsigned short* __restrict__ kth, unsigned short* __restrict__ ktl)
{
    __shared__ unsigned pk[64][65];
    const int b = blockIdx.x;
    const int kh = b >> 7, tt = (b >> 1) & 63, hh = b & 1;
    const int t0 = tt * 64, d0 = hh * 64;
    const int tid = threadIdx.x;
    #pragma unroll
    for (int e = 0; e < 16; ++e) {
        const int lin = e * 256 + tid;
        const int tl = lin >> 6, dl = lin & 63;
        const size_t o = ((size_t)kh * T_LEN + t0 + tl) * DKn + d0 + dl;
        pk[tl][dl] = ((unsigned)ksh[o] << 16) | (unsigned)ksl[o];
    }
    __syncthreads();
    #pragma unroll
    for (int e = 0; e < 16; ++e) {
        const int lin = e * 256 + tid;
        const int dl = lin >> 6, tl = lin & 63;
        const unsigned v = pk[tl][dl];
        const size_t o = ((size_t)kh * DKn + d0 + dl) * T_LEN + t0 + tl;
        kth[o] = (unsigned short)(v >> 16);
        ktl[o] = (unsigned short)(v & 0xFFFF);
    }
}

// ---------------- phase 1: per (head, chunk): G, A, M, solve -> U (in va2), -W ----------------
__global__ __launch_bounds__(256) void k_p1(
    const float2* __restrict__ gbl,
    const unsigned short* __restrict__ qsh, const unsigned short* __restrict__ qsl,
    const unsigned short* __restrict__ ksh, const unsigned short* __restrict__ ksl,
    float* __restrict__ va2, float* __restrict__ Gbuf,
    unsigned short* __restrict__ Wh, unsigned short* __restrict__ Wl,
    unsigned short* __restrict__ Mh, unsigned short* __restrict__ Ml)
{
    __shared__ float sA[64][68];
    __shared__ float sG[64];
    __shared__ float sB[64];
    const int blk = blockIdx.x;
    const int h = blk >> 6, ch = blk & 63;
    const int kh = h >> 1, t0 = ch * 64;
    const int tid = threadIdx.x, lane = tid & 63, wid = tid >> 6;
    const int l15 = lane & 15, lg = lane >> 4;

    if (tid < 64) {
        float2 g2 = gbl[(size_t)h * T_LEN + t0 + tid];
        sB[tid] = g2.x;
        float G = g2.y;
        #pragma unroll
        for (int s = 1; s < 64; s <<= 1) {
            float y = __int_as_float(__builtin_amdgcn_ds_bpermute((tid - s) << 2, __float_as_int(G)));
            G += (tid >= s) ? y : 0.f;
        }
        sG[tid] = G;
        Gbuf[(size_t)h * T_LEN + t0 + tid] = G;
    }
    __syncthreads();

    // MFMA: KK (strict lower) and QK (lower incl diag), split bf16
    const char TIa[10] = {0,1,1,2,2,2,3,3,3,3};
    const char TJa[10] = {0,0,1,0,1,2,0,1,2,3};
    const size_t kbase = ((size_t)kh * T_LEN + t0) * DKn;
    for (int idx = wid; idx < 10; idx += 4) {
        const int mi = TIa[idx], nj = TJa[idx];
        f32x4 aKK = {0.f,0.f,0.f,0.f}, aQK = {0.f,0.f,0.f,0.f};
        #pragma unroll
        for (int kk = 0; kk < 4; ++kk) {
            const size_t offA = kbase + (size_t)(16*mi + l15) * DKn + 32*kk + 8*lg;
            const size_t offB = kbase + (size_t)(16*nj + l15) * DKn + 32*kk + 8*lg;
            short8 kAh = *(const short8*)(ksh + offA);
            short8 kAl = *(const short8*)(ksl + offA);
            short8 kBh = *(const short8*)(ksh + offB);
            short8 kBl = *(const short8*)(ksl + offB);
            short8 qAh = *(const short8*)(qsh + offA);
            short8 qAl = *(const short8*)(qsl + offA);
            aKK = MF(kAh,kBh,aKK); aKK = MF(kAh,kBl,aKK); aKK = MF(kAl,kBh,aKK);
            aQK = MF(qAh,kBh,aQK); aQK = MF(qAh,kBl,aQK); aQK = MF(qAl,kBh,aQK);
        }
        #pragma unroll
        for (int r = 0; r < 4; ++r) {
            const int i = 16*mi + 4*lg + r;
            const int j = 16*nj + l15;
            const float e = __expf(fminf(sG[i] - sG[j], 0.f));
            sA[i][j] = (j < i) ? sB[i] * e * aKK[r] : 0.f;
            const float mv = (j <= i) ? e * aQK[r] : 0.f;
            unsigned short mh, ml; bsplit(mv, mh, ml);
            const size_t moff = (((size_t)h * NCH + ch) * CS + i) * CS + j;
            Mh[moff] = mh; Ml[moff] = ml;
        }
    }
    __syncthreads();

    // forward substitution: (I+A) X = RHS; cols 0..127 = U, 128..255 = W
    const int c = tid;
    float X[64];
    if (c < 128) {
        #pragma unroll
        for (int i = 0; i < 64; ++i)
            X[i] = va2[((size_t)h * T_LEN + t0 + i) * DVn + c];
    } else {
        const int dk = c - 128;
        #pragma unroll
        for (int i = 0; i < 64; ++i) {
            const size_t o = ((size_t)kh * T_LEN + t0 + i) * DKn + dk;
            const float kf = bf16tof(ksh[o]) + bf16tof(ksl[o]);
            X[i] = sB[i] * __expf(sG[i]) * kf;
        }
    }
    #pragma unroll
    for (int i = 1; i < 64; ++i) {
        float acc = X[i];
        const int nq = (i + 3) >> 2;
        #pragma unroll
        for (int q = 0; q < nq; ++q) {
            const f32x4 aa = *(const f32x4*)&sA[i][4*q];
            acc = fmaf(-aa[0], X[4*q+0], acc);
            acc = fmaf(-aa[1], X[4*q+1], acc);
            acc = fmaf(-aa[2], X[4*q+2], acc);
            acc = fmaf(-aa[3], X[4*q+3], acc);
        }
        X[i] = acc;
    }
    if (c < 128) {
        #pragma unroll
        for (int i = 0; i < 64; ++i)
            va2[((size_t)h * T_LEN + t0 + i) * DVn + c] = X[i];   // U in place
    } else {
        const int dk = c - 128;
        #pragma unroll
        for (int i = 0; i < 64; ++i) {
            unsigned short wh, wl; bsplit(-X[i], wh, wl);         // store -W
            const size_t o = (((size_t)h * NCH + ch) * CS + i) * DKn + dk;
            Wh[o] = wh; Wl[o] = wl;
        }
    }
}

// ---------------- phase 2: R15 structure (ping-pong ChBuf, BARL) + 3-chain splits ----------------
struct ChBuf {
    short8 qh[4], ql[4];
    short8 wh[4], wl[4];
    short8 mh[2], ml[2];
    short8 th[2][2], tl[2][2];
    float  u[4];
    f32x4  g4;
    float  g63;
};

__device__ __forceinline__ void issue_ch(ChBuf& B, int ch,
    const unsigned short* __restrict__ qsh, const unsigned short* __restrict__ qsl,
    const unsigned short* __restrict__ kth, const unsigned short* __restrict__ ktl,
    const unsigned short* __restrict__ Wh, const unsigned short* __restrict__ Wl,
    const unsigned short* __restrict__ Mh, const unsigned short* __restrict__ Ml,
    const float* __restrict__ va2, const float* __restrict__ Gbuf,
    int h, int kh, int n0, int wid, int l15, int lg)
{
    const int t0 = ch * CS;
    const size_t qbase = ((size_t)kh * T_LEN + t0 + 16*wid + l15) * DKn;
    #pragma unroll
    for (int kk = 0; kk < 4; ++kk) {
        B.qh[kk] = *(const short8*)(qsh + qbase + 32*kk + 8*lg);
        B.ql[kk] = *(const short8*)(qsl + qbase + 32*kk + 8*lg);
    }
    const size_t wbase = (((size_t)h * NCH + ch) * CS + 16*wid + l15) * DKn;
    #pragma unroll
    for (int kk = 0; kk < 4; ++kk) {
        B.wh[kk] = *(const short8*)(Wh + wbase + 32*kk + 8*lg);
        B.wl[kk] = *(const short8*)(Wl + wbase + 32*kk + 8*lg);
    }
    const size_t mbase = (((size_t)h * NCH + ch) * CS + 16*wid + l15) * CS;
    #pragma unroll
    for (int k2 = 0; k2 < 2; ++k2) {
        B.mh[k2] = *(const short8*)(Mh + mbase + 32*k2 + 8*lg);
        B.ml[k2] = *(const short8*)(Ml + mbase + 32*k2 + 8*lg);
    }
    #pragma unroll
    for (int m2 = 0; m2 < 2; ++m2) {
        const size_t kb2 = ((size_t)kh * DKn + 16*(wid + 4*m2) + l15) * T_LEN + t0;
        #pragma unroll
        for (int k2 = 0; k2 < 2; ++k2) {
            B.th[m2][k2] = *(const short8*)(kth + kb2 + 32*k2 + 8*lg);
            B.tl[m2][k2] = *(const short8*)(ktl + kb2 + 32*k2 + 8*lg);
        }
    }
    #pragma unroll
    for (int r = 0; r < 4; ++r)
        B.u[r] = va2[((size_t)h * T_LEN + t0 + 16*wid + 4*lg + r) * DVn + n0 + l15];
    const float* gp = Gbuf + (size_t)h * T_LEN + t0;
    B.g4  = *(const f32x4*)(gp + 16*wid + 4*lg);
    B.g63 = gp[63];
}

__device__ __forceinline__ void compute_ch(const ChBuf& B, int ch,
    unsigned (*sSp)[132], unsigned (*sDLp)[68], unsigned (*sDSp)[68],
    short8* Sbh, short8* Sbl, f32x4* Sc,
    float* __restrict__ out,
    int h, int n0, int wid, int l15, int lg)
{
    const int t0 = ch * CS;
    const float g63 = B.g63;
    const float gr[4] = {B.g4[0], B.g4[1], B.g4[2], B.g4[3]};

    // DL = U + (-W) @ S   (3 independent chains)
    f32x4 d0 = {B.u[0], B.u[1], B.u[2], B.u[3]};
    f32x4 d1 = {0.f,0.f,0.f,0.f}, d2 = {0.f,0.f,0.f,0.f};
    #pragma unroll
    for (int kk = 0; kk < 4; ++kk) {
        d0 = MF(B.wh[kk], Sbh[kk], d0);
        d1 = MF(B.wh[kk], Sbl[kk], d1);
        d2 = MF(B.wl[kk], Sbh[kk], d2);
    }
    f32x4 dl;
    #pragma unroll
    for (int r = 0; r < 4; ++r) dl[r] = d0[r] + d1[r] + d2[r];

    // write packed DL, DS (= DL * exp(G63 - G_t))
    const int cc0 = 16*wid + 4*lg;
    u32x4 pdl, pds;
    #pragma unroll
    for (int r = 0; r < 4; ++r) {
        pdl[r] = packsplit(dl[r]);
        pds[r] = packsplit(dl[r] * __expf(g63 - gr[r]));
    }
    *(u32x4*)&sDLp[l15][cc0] = pdl;
    *(u32x4*)&sDSp[l15][cc0] = pds;
    BARL();                                  // barrier 1: DL/DS visible

    // read DL/DS B-frags
    short8 dlh[2], dll[2], dsh[2], dsl[2];
    #pragma unroll
    for (int k2 = 0; k2 < 2; ++k2) {
        u32x4 x0 = *(const u32x4*)&sDLp[l15][32*k2 + 8*lg];
        u32x4 x1 = *(const u32x4*)&sDLp[l15][32*k2 + 8*lg + 4];
        unpack8(x0, x1, dlh[k2], dll[k2]);
        u32x4 y0 = *(const u32x4*)&sDSp[l15][32*k2 + 8*lg];
        u32x4 y1 = *(const u32x4*)&sDSp[l15][32*k2 + 8*lg + 4];
        unpack8(y0, y1, dsh[k2], dsl[k2]);
    }

    // O = exp(G_i)*(Q@S) + M@DL   (3 chains each)
    f32x4 a0 = {0.f,0.f,0.f,0.f}, a1 = {0.f,0.f,0.f,0.f}, a2 = {0.f,0.f,0.f,0.f};
    f32x4 m0 = {0.f,0.f,0.f,0.f}, m1 = {0.f,0.f,0.f,0.f}, m2c = {0.f,0.f,0.f,0.f};
    #pragma unroll
    for (int kk = 0; kk < 4; ++kk) {
        a0 = MF(B.qh[kk], Sbh[kk], a0);
        a1 = MF(B.qh[kk], Sbl[kk], a1);
        a2 = MF(B.ql[kk], Sbh[kk], a2);
    }
    #pragma unroll
    for (int k2 = 0; k2 < 2; ++k2) {
        m0 = MF(B.mh[k2], dlh[k2], m0);
        m1 = MF(B.mh[k2], dll[k2], m1);
        m2c = MF(B.ml[k2], dlh[k2], m2c);
    }
    #pragma unroll
    for (int r = 0; r < 4; ++r) {
        const int cc = cc0 + r;
        const float aq = a0[r] + a1[r] + a2[r];
        const float am = m0[r] + m1[r] + m2c[r];
        out[((size_t)(t0 + cc) * HVn + h) * DVn + n0 + l15] = fmaf(__expf(gr[r]), aq, am);
    }

    // S' = lam*S + K^T @ DS   (3 chains per m2)
    const float lam = __expf(g63);
    #pragma unroll
    for (int m2 = 0; m2 < 2; ++m2) {
        f32x4 t0a = {0.f,0.f,0.f,0.f}, t1a = {0.f,0.f,0.f,0.f}, t2a = {0.f,0.f,0.f,0.f};
        #pragma unroll
        for (int k2 = 0; k2 < 2; ++k2) {
            t0a = MF(B.th[m2][k2], dsh[k2], t0a);
            t1a = MF(B.th[m2][k2], dsl[k2], t1a);
            t2a = MF(B.tl[m2][k2], dsh[k2], t2a);
        }
        u32x4 ps;
        #pragma unroll
        for (int r = 0; r < 4; ++r) {
            Sc[m2][r] = fmaf(lam, Sc[m2][r], t0a[r] + t1a[r] + t2a[r]);
            ps[r] = packsplit(Sc[m2][r]);
        }
        *(u32x4*)&sSp[l15][16*wid + 64*m2 + 4*lg] = ps;
    }
    BARL();                                  // barrier 2: S visible

    // refresh register B-frag copy of S for next chunk
    #pragma unroll
    for (int kk = 0; kk < 4; ++kk) {
        u32x4 z0 = *(const u32x4*)&sSp[l15][32*kk + 8*lg];
        u32x4 z1 = *(const u32x4*)&sSp[l15][32*kk + 8*lg + 4];
        unpack8(z0, z1, Sbh[kk], Sbl[kk]);
    }
}

__global__ __launch_bounds__(256, 1) void k_p2(
    const unsigned short* __restrict__ qsh, const unsigned short* __restrict__ qsl,
    const unsigned short* __restrict__ kth, const unsigned short* __restrict__ ktl,
    const unsigned short* __restrict__ Wh, const unsigned short* __restrict__ Wl,
    const unsigned short* __restrict__ Mh, const unsigned short* __restrict__ Ml,
    const float* __restrict__ va2, const float* __restrict__ Gbuf,
    float* __restrict__ out)
{
    __shared__ unsigned sSp[16][132];
    __shared__ unsigned sDLp[16][68];
    __shared__ unsigned sDSp[16][68];

    // XCD co-location: all 8 dv-slices of a head on one XCD; 4 heads per XCD.
    const int p = blockIdx.x;
    const int slot = p >> 3;
    const int h  = (p & 7) * 4 + (slot & 3);
    const int nb = slot >> 2;
    const int kh = h >> 1, n0 = nb * 16;
    const int tid = threadIdx.x, lane = tid & 63, wid = tid >> 6;
    const int l15 = lane & 15, lg = lane >> 4;

    short8 Sbh[4], Sbl[4];
    f32x4 Sc[2];
    const short8 z8 = {0,0,0,0,0,0,0,0};
    #pragma unroll
    for (int kk = 0; kk < 4; ++kk) { Sbh[kk] = z8; Sbl[kk] = z8; }
    Sc[0] = (f32x4){0.f,0.f,0.f,0.f};
    Sc[1] = (f32x4){0.f,0.f,0.f,0.f};

    ChBuf bufA, bufB;
    issue_ch(bufA, 0, qsh, qsl, kth, ktl, Wh, Wl, Mh, Ml, va2, Gbuf,
             h, kh, n0, wid, l15, lg);

    #pragma unroll 1
    for (int ch2 = 0; ch2 < NCH / 2; ++ch2) {
        const int ch = 2 * ch2;
        SB0();
        issue_ch(bufB, ch + 1, qsh, qsl, kth, ktl, Wh, Wl, Mh, Ml, va2, Gbuf,
                 h, kh, n0, wid, l15, lg);
        SB0();
        compute_ch(bufA, ch, sSp, sDLp, sDSp, Sbh, Sbl, Sc, out, h, n0, wid, l15, lg);
        SB0();
        if (ch + 2 < NCH)
            issue_ch(bufA, ch + 2, qsh, qsl, kth, ktl, Wh, Wl, Mh, Ml, va2, Gbuf,
                     h, kh, n0, wid, l15, lg);
        SB0();
        compute_ch(bufB, ch + 1, sSp, sDLp, sDSp, Sbh, Sbl, Sc, out, h, n0, wid, l15, lg);
    }
}

extern "C" void kernel_launch(void* const* d_in, const int* in_sizes, int n_in,
                              void* d_out, int out_size, void* d_ws, size_t ws_size,
                              hipStream_t stream) {
    const float* mixed_qkv = (const float*)d_in[0];
    const float* a         = (const float*)d_in[1];
    const float* b         = (const float*)d_in[2];
    const float* conv_w    = (const float*)d_in[3];
    const float* dt_bias   = (const float*)d_in[4];
    const float* alog      = (const float*)d_in[5];
    float* out = (float*)d_out;
    char* ws = (char*)d_ws;

    unsigned short* qsh = (unsigned short*)(ws + OFF_QSH);
    unsigned short* qsl = (unsigned short*)(ws + OFF_QSL);
    unsigned short* ksh = (unsigned short*)(ws + OFF_KSH);
    unsigned short* ksl = (unsigned short*)(ws + OFF_KSL);
    unsigned short* kth = (unsigned short*)(ws + OFF_KTH);
    unsigned short* ktl = (unsigned short*)(ws + OFF_KTL);
    float*  va2 = (float*)(ws + OFF_VA);
    float2* gbl = (float2*)(ws + OFF_GBL);
    float*  Gbf = (float*)(ws + OFF_G);
    unsigned short* Wh = (unsigned short*)(ws + OFF_WH);
    unsigned short* Wl = (unsigned short*)(ws + OFF_WL);
    unsigned short* Mh = (unsigned short*)(ws + OFF_MH);
    unsigned short* Ml = (unsigned short*)(ws + OFF_ML);

    k_gate<<<(T_LEN * HVn + 255) / 256, 256, 0, stream>>>(a, b, dt_bias, alog, gbl);

    dim3 cgrid(T_LEN, 16);
    k_conv<<<cgrid, 128, 0, stream>>>(mixed_qkv, conv_w, b, qsh, qsl, ksh, ksl, va2);

    k_tr<<<2048, 256, 0, stream>>>(ksh, ksl, kth, ktl);

    k_p1<<<HVn * NCH, 256, 0, stream>>>(gbl, qsh, qsl, ksh, ksl, va2, Gbf, Wh, Wl, Mh, Ml);

    k_p2<<<HVn * 8, 256, 0, stream>>>(qsh, qsl, kth, ktl, Wh, Wl, Mh, Ml, va2, Gbf, out);
}